// Round 13
// baseline (188.184 us; speedup 1.0000x reference)
//
#include <hip/hip_runtime.h>

// ---------------------------------------------------------------------------
// Round 13: k_featval compute sections split into phases with setprio (T3+T5).
//  feat loop : 4 phases (mi pairs), each {4 ds_read; lgkm0; SB; prio1; 24 MFMA;
//              prio0; s_barrier}. Staging stays bulk-at-step-top (counted vmcnt
//              unchanged — in-phase staging would force a drain at boundaries).
//  value loop: 2 phases x 16 MFMA, same pattern.
//  k_xsplit / k_cluster / k_proj: r12 exact.
// ws: [0,64M) feat_T | [64M,96M) xh->outpT | [96M,128M) xl->value_T | +12KB part
// d_out scratch (ALL consumed before k_proj writes): fwh fwl vwh centers_f/v
// ---------------------------------------------------------------------------

#define HW 1024

typedef _Float16 f16x8 __attribute__((ext_vector_type(8)));
typedef float f32x4 __attribute__((ext_vector_type(4)));

union H4 { uint2 u; _Float16 h[4]; };
union H8 { uint4 u; _Float16 h[8]; };
union H2 { unsigned int u; _Float16 h[2]; };
union F4 { float4 v; float f[4]; };

__device__ __forceinline__ void gld16(const _Float16* g, _Float16* l) {
    __builtin_amdgcn_global_load_lds(
        (const __attribute__((address_space(1))) void*)g,
        (__attribute__((address_space(3))) void*)l, 16, 0, 0);
}

// ---------------- k_xsplit: transpose + fp16 split, + weight pre-split ----------------
__global__ __launch_bounds__(256) void k_xsplit(
    const float* __restrict__ x,
    _Float16* __restrict__ xh, _Float16* __restrict__ xl,
    const float* __restrict__ fw, const float* __restrict__ vw,
    _Float16* __restrict__ fwh, _Float16* __restrict__ fwl,
    _Float16* __restrict__ vwh)
{
    __shared__ float tile[64][65];
    const int t = threadIdx.x;
    const int b = blockIdx.z;
    const int k0 = blockIdx.y * 64;
    const int n0 = blockIdx.x * 64;

    if (b == 0) {
        const int c0 = (blockIdx.x * 8 + blockIdx.y) * 2;
#pragma unroll
        for (int u = 0; u < 2; ++u) {
            const int i = ((c0 + u) * 256 + t) * 4;
            F4 a;
            a.v = *(const float4*)&fw[i];
            H4 h, l;
#pragma unroll
            for (int j = 0; j < 4; ++j) {
                const float s = a.f[j] * 256.f;
                h.h[j] = (_Float16)s;
                l.h[j] = (_Float16)(s - (float)h.h[j]);
            }
            *(uint2*)&fwh[i] = h.u;
            *(uint2*)&fwl[i] = l.u;
            a.v = *(const float4*)&vw[i];
#pragma unroll
            for (int j = 0; j < 4; ++j) h.h[j] = (_Float16)(a.f[j] * 256.f);
            *(uint2*)&vwh[i] = h.u;
        }
    }

    const float* Xb = x + (size_t)b * (512 * HW);
#pragma unroll
    for (int j = 0; j < 16; ++j) {
        const int k = j * 4 + (t >> 6);
        const int n = t & 63;
        tile[k][n] = Xb[(size_t)(k0 + k) * HW + n0 + n];
    }
    __syncthreads();
#pragma unroll
    for (int j = 0; j < 8; ++j) {
        const int n = j * 8 + (t >> 5);
        const int kp = t & 31;
        const float s0 = tile[kp * 2][n] * 256.f;
        const float s1 = tile[kp * 2 + 1][n] * 256.f;
        H2 hh, hl;
        hh.h[0] = (_Float16)s0;
        hh.h[1] = (_Float16)s1;
        hl.h[0] = (_Float16)(s0 - (float)hh.h[0]);
        hl.h[1] = (_Float16)(s1 - (float)hh.h[1]);
        const size_t o = ((size_t)b * 1024 + n0 + n) * 512 + k0 + kp * 2;
        *(unsigned int*)&xh[o] = hh.u;
        *(unsigned int*)&xl[o] = hl.u;
    }
}

// ---------------- k_featval: phase-split compute + setprio ----------------
__global__ __launch_bounds__(512, 2) void k_featval(
    const _Float16* __restrict__ fwh, const _Float16* __restrict__ fwl,
    const _Float16* __restrict__ vwh,
    const float* __restrict__ f_b, const float* __restrict__ v_b,
    const _Float16* __restrict__ xh, const _Float16* __restrict__ xl,
    float* __restrict__ feat_T, float* __restrict__ centers_f,
    _Float16* __restrict__ value_T, float* __restrict__ centers_v)
{
    __shared__ _Float16 Ah[2][8192], Al[2][8192], Bh[2][8192], Bl[2][8192]; // 128 KB
    __shared__ float pool_lds[4][4][256];                                   // 16 KB
    const int t = threadIdx.x, lane = t & 63, wv = t >> 6;

    // T1 remap: bid = u*16 + r; yy=r>>3; v=u*8+(r&7); xx=v&3; zz=v>>2
    const int bid = blockIdx.x;
    const int r_ = bid & 15, u_ = bid >> 4;
    const int yy = r_ >> 3;
    const int v_ = u_ * 8 + (r_ & 7);
    const int xx = v_ & 3, zz = v_ >> 2;

    const int b = zz, o0 = yy * 256, p0 = xx * 256;
    const int wr = wv >> 2, wc = wv & 3;

    f32x4 acc[8][4];
#pragma unroll
    for (int i = 0; i < 8; ++i)
#pragma unroll
        for (int j = 0; j < 4; ++j) acc[i][j] = (f32x4){0.f, 0.f, 0.f, 0.f};

    const int gslot = ((lane & 3) ^ ((lane >> 3) & 3)) * 8;
    const _Float16* ash = fwh + (size_t)(o0 + wv * 32 + (lane >> 2)) * 512 + gslot;
    const _Float16* asl = fwl + (size_t)(o0 + wv * 32 + (lane >> 2)) * 512 + gslot;
    const _Float16* asv = vwh + (size_t)(o0 + wv * 32 + (lane >> 2)) * 512 + gslot;
    const size_t brow = (size_t)b * 1024 + p0 + wv * 32 + (lane >> 2);
    const _Float16* bsh = xh + brow * 512 + gslot;
    const _Float16* bsl = xl + brow * 512 + gslot;

#define STAGE_F(d, k0)                                              \
    {                                                               \
        gld16(ash + (k0),        &Ah[(d)][(wv * 32) * 32]);         \
        gld16(ash + (k0) + 8192, &Ah[(d)][(wv * 32 + 16) * 32]);    \
        gld16(asl + (k0),        &Al[(d)][(wv * 32) * 32]);         \
        gld16(asl + (k0) + 8192, &Al[(d)][(wv * 32 + 16) * 32]);    \
        gld16(bsh + (k0),        &Bh[(d)][(wv * 32) * 32]);         \
        gld16(bsh + (k0) + 8192, &Bh[(d)][(wv * 32 + 16) * 32]);    \
        gld16(bsl + (k0),        &Bl[(d)][(wv * 32) * 32]);         \
        gld16(bsl + (k0) + 8192, &Bl[(d)][(wv * 32 + 16) * 32]);    \
    }
#define STAGE_W(d, k0)                                              \
    {                                                               \
        gld16(asv + (k0),        &Ah[(d)][(wv * 32) * 32]);         \
        gld16(asv + (k0) + 8192, &Ah[(d)][(wv * 32 + 16) * 32]);    \
        gld16(bsh + (k0),        &Bh[(d)][(wv * 32) * 32]);         \
        gld16(bsh + (k0) + 8192, &Bh[(d)][(wv * 32 + 16) * 32]);    \
    }

    STAGE_F(0, 0);
    const int slA = ((lane >> 4) ^ ((lane >> 1) & 3)) * 8;
    int cur = 0;
    for (int kb = 0; kb < 16; ++kb) {
        if (kb < 15) {
            STAGE_F(cur ^ 1, (kb + 1) * 32);
            asm volatile("s_waitcnt vmcnt(8)" ::: "memory");
        } else {
            asm volatile("s_waitcnt vmcnt(0)" ::: "memory");
        }
        __builtin_amdgcn_sched_barrier(0);
        __builtin_amdgcn_s_barrier();       // buf[cur] ready on all waves
        // B fragments (live across phases)
        f16x8 bh4[4], bl4[4];
#pragma unroll
        for (int j = 0; j < 4; ++j) {
            const int bo = (wc * 64 + j * 16 + (lane & 15)) * 32 + slA;
            bh4[j] = *(f16x8*)&Bh[cur][bo];
            bl4[j] = *(f16x8*)&Bl[cur][bo];
        }
        // 4 phases: mi pairs {0,1},{2,3},{4,5},{6,7}
#pragma unroll
        for (int ph = 0; ph < 4; ++ph) {
            f16x8 ah2[2], al2[2];
#pragma unroll
            for (int q = 0; q < 2; ++q) {
                const int mi = ph * 2 + q;
                const int ao = (wr * 128 + mi * 16 + (lane & 15)) * 32 + slA;
                ah2[q] = *(f16x8*)&Ah[cur][ao];
                al2[q] = *(f16x8*)&Al[cur][ao];
            }
            asm volatile("s_waitcnt lgkmcnt(0)" ::: "memory");
            __builtin_amdgcn_sched_barrier(0);              // rule 18
            __builtin_amdgcn_s_setprio(1);
#pragma unroll
            for (int q = 0; q < 2; ++q) {
                const int mi = ph * 2 + q;
#pragma unroll
                for (int nj = 0; nj < 4; ++nj) {
                    acc[mi][nj] = __builtin_amdgcn_mfma_f32_16x16x32_f16(ah2[q], bh4[nj], acc[mi][nj], 0, 0, 0);
                    acc[mi][nj] = __builtin_amdgcn_mfma_f32_16x16x32_f16(ah2[q], bl4[nj], acc[mi][nj], 0, 0, 0);
                    acc[mi][nj] = __builtin_amdgcn_mfma_f32_16x16x32_f16(al2[q], bh4[nj], acc[mi][nj], 0, 0, 0);
                }
            }
            __builtin_amdgcn_s_setprio(0);
            __builtin_amdgcn_s_barrier();   // phase end; final one guards buf overwrite
        }
        cur ^= 1;
    }

    STAGE_W(0, 0);   // value prologue issued early (T14)

    // ---- feat epilogue ----
    const int pj = (lane >> 3) & 1;
    {
        float ps[32][2];
#pragma unroll
        for (int mi = 0; mi < 8; ++mi) {
            const int obase = o0 + wr * 128 + mi * 16 + (lane >> 4) * 4;
            F4 bs4;
            bs4.v = *(const float4*)&f_b[obase];
#pragma unroll
            for (int r = 0; r < 4; ++r) { ps[mi * 4 + r][0] = 0.f; ps[mi * 4 + r][1] = 0.f; }
#pragma unroll
            for (int nj = 0; nj < 4; ++nj) {
                const int p = p0 + wc * 64 + nj * 16 + (lane & 15);
                F4 vv;
#pragma unroll
                for (int r = 0; r < 4; ++r) {
                    vv.f[r] = acc[mi][nj][r] * (1.f / 65536.f) + bs4.f[r];
                    ps[mi * 4 + r][nj & 1] += vv.f[r];
                }
                *(float4*)&feat_T[((size_t)b * 1024 + p) * 512 + obase] = vv.v;
            }
        }
#pragma unroll
        for (int q = 0; q < 32; ++q)
#pragma unroll
            for (int f2s = 0; f2s < 2; ++f2s) {
                ps[q][f2s] += __shfl_xor(ps[q][f2s], 1);
                ps[q][f2s] += __shfl_xor(ps[q][f2s], 2);
                ps[q][f2s] += __shfl_xor(ps[q][f2s], 4);
            }
        if ((lane & 7) == 0) {
#pragma unroll
            for (int mi = 0; mi < 8; ++mi)
#pragma unroll
                for (int r = 0; r < 4; ++r) {
                    const int ol = wr * 128 + mi * 16 + (lane >> 4) * 4 + r;
                    pool_lds[wc][0 * 2 + pj][ol] = ps[mi * 4 + r][0];
                    pool_lds[wc][1 * 2 + pj][ol] = ps[mi * 4 + r][1];
                }
        }
        __syncthreads();
#pragma unroll
        for (int u = 0; u < 2; ++u) {
            const int idx = u * 512 + t;
            const int g = idx >> 8, o = idx & 255;
            const float s = pool_lds[0][g][o] + pool_lds[1][g][o]
                          + pool_lds[2][g][o] + pool_lds[3][g][o];
            centers_f[(((size_t)b * 8 + 2 * xx) * 4 + g) * 512 + o0 + o] = s;
            centers_f[(((size_t)b * 8 + 2 * xx + 1) * 4 + g) * 512 + o0 + o] = 0.f;
        }
    }

    // ---- fused value K-loop (2 phases x 16 MFMA) ----
    f32x4 vacc[8][4];
#pragma unroll
    for (int i = 0; i < 8; ++i)
#pragma unroll
        for (int j = 0; j < 4; ++j) vacc[i][j] = (f32x4){0.f, 0.f, 0.f, 0.f};

    cur = 0;
    for (int kb = 0; kb < 16; ++kb) {
        if (kb < 15) {
            STAGE_W(cur ^ 1, (kb + 1) * 32);
            asm volatile("s_waitcnt vmcnt(4)" ::: "memory");
        } else {
            asm volatile("s_waitcnt vmcnt(0)" ::: "memory");
        }
        __builtin_amdgcn_sched_barrier(0);
        __builtin_amdgcn_s_barrier();
        f16x8 bh4[4];
#pragma unroll
        for (int j = 0; j < 4; ++j)
            bh4[j] = *(f16x8*)&Bh[cur][(wc * 64 + j * 16 + (lane & 15)) * 32 + slA];
#pragma unroll
        for (int ph = 0; ph < 2; ++ph) {
            f16x8 ah4[4];
#pragma unroll
            for (int q = 0; q < 4; ++q) {
                const int mi = ph * 4 + q;
                ah4[q] = *(f16x8*)&Ah[cur][(wr * 128 + mi * 16 + (lane & 15)) * 32 + slA];
            }
            asm volatile("s_waitcnt lgkmcnt(0)" ::: "memory");
            __builtin_amdgcn_sched_barrier(0);
            __builtin_amdgcn_s_setprio(1);
#pragma unroll
            for (int q = 0; q < 4; ++q) {
                const int mi = ph * 4 + q;
#pragma unroll
                for (int nj = 0; nj < 4; ++nj)
                    vacc[mi][nj] = __builtin_amdgcn_mfma_f32_16x16x32_f16(ah4[q], bh4[nj], vacc[mi][nj], 0, 0, 0);
            }
            __builtin_amdgcn_s_setprio(0);
            __builtin_amdgcn_s_barrier();
        }
        cur ^= 1;
    }
#undef STAGE_F
#undef STAGE_W

    // ---- value epilogue ----
    {
        float ps[32][2];
#pragma unroll
        for (int mi = 0; mi < 8; ++mi) {
            const int obase = o0 + wr * 128 + mi * 16 + (lane >> 4) * 4;
            F4 bs4;
            bs4.v = *(const float4*)&v_b[obase];
#pragma unroll
            for (int r = 0; r < 4; ++r) { ps[mi * 4 + r][0] = 0.f; ps[mi * 4 + r][1] = 0.f; }
#pragma unroll
            for (int nj = 0; nj < 4; ++nj) {
                const int p = p0 + wc * 64 + nj * 16 + (lane & 15);
                H4 hv;
#pragma unroll
                for (int r = 0; r < 4; ++r) {
                    const float v = vacc[mi][nj][r] * (1.f / 65536.f) + bs4.f[r];
                    ps[mi * 4 + r][nj & 1] += v;
                    hv.h[r] = (_Float16)v;
                }
                *(uint2*)&value_T[((size_t)b * 1024 + p) * 512 + obase] = hv.u;
            }
        }
#pragma unroll
        for (int q = 0; q < 32; ++q)
#pragma unroll
            for (int f2s = 0; f2s < 2; ++f2s) {
                ps[q][f2s] += __shfl_xor(ps[q][f2s], 1);
                ps[q][f2s] += __shfl_xor(ps[q][f2s], 2);
                ps[q][f2s] += __shfl_xor(ps[q][f2s], 4);
            }
        __syncthreads();
        if ((lane & 7) == 0) {
#pragma unroll
            for (int mi = 0; mi < 8; ++mi)
#pragma unroll
                for (int r = 0; r < 4; ++r) {
                    const int ol = wr * 128 + mi * 16 + (lane >> 4) * 4 + r;
                    pool_lds[wc][0 * 2 + pj][ol] = ps[mi * 4 + r][0];
                    pool_lds[wc][1 * 2 + pj][ol] = ps[mi * 4 + r][1];
                }
        }
        __syncthreads();
#pragma unroll
        for (int u = 0; u < 2; ++u) {
            const int idx = u * 512 + t;
            const int g = idx >> 8, o = idx & 255;
            const float s = pool_lds[0][g][o] + pool_lds[1][g][o]
                          + pool_lds[2][g][o] + pool_lds[3][g][o];
            centers_v[(((size_t)b * 8 + 2 * xx) * 4 + g) * 512 + o0 + o] = s;
            centers_v[(((size_t)b * 8 + 2 * xx + 1) * 4 + g) * 512 + o0 + o] = 0.f;
        }
    }
}

// ---------------- k_cluster: r10/r12 exact ----------------
__global__ __launch_bounds__(256) void k_cluster(
    const float* __restrict__ feat_T, const _Float16* __restrict__ value_T,
    const float* __restrict__ centers_f, const float* __restrict__ centers_v,
    const float* __restrict__ alpha_p, const float* __restrict__ beta_p,
    _Float16* __restrict__ outpT, float* __restrict__ part)
{
    __shared__ float cnl[4][64];
    __shared__ float vcl[4][64];
    __shared__ float obuf[4][68];
    __shared__ int   sidx[256];
    __shared__ float sbest[256];
    __shared__ float scrt[4][4][64];
    __shared__ int   cntw[4][4];
    __shared__ float red[8];
    __shared__ float gsc[16];

    const int t = threadIdx.x, lane = t & 63, wv = t >> 6;
    const int bp = blockIdx.x;
    const int f2 = bp & 1, f1 = (bp >> 1) & 1, head = (bp >> 2) & 7, b = bp >> 5;

    const int m = wv, cc = lane;
    const int pi = m >> 1, pj = m & 1, g = f2 * 2 + pj;
    const int pt = 4 * f1 + 2 * pi;
    {
        const float* cf = centers_f + (((size_t)b * 8 + pt) * 4 + g) * 512 + head * 64 + cc;
        const float c = (cf[0] + cf[4 * 512]) * (1.f / 64.f);
        float ss = c * c;
#pragma unroll
        for (int off = 32; off > 0; off >>= 1) ss += __shfl_xor(ss, off);
        const float inv = 1.f / fmaxf(sqrtf(ss), 1e-12f);
        cnl[m][cc] = c * inv;
        const float* cv = centers_v + (((size_t)b * 8 + pt) * 4 + g) * 512 + head * 64 + cc;
        vcl[m][cc] = (cv[0] + cv[4 * 512]) * (1.f / 64.f);
    }
    __syncthreads();

    if (t < 16) {
        const int gm = t >> 2, gk = t & 3;
        float gg = 0.f;
        for (int c = 0; c < 64; ++c) gg += cnl[gm][c] * cnl[gk][c];
        const float d = gg - (gm == gk ? 1.f : 0.f);
        gsc[t] = d * d;
    }

    const float alpha = alpha_p[0], beta = beta_p[0];
    const int n = t;
    const int pg = (f1 * 16 + (n >> 4)) * 32 + f2 * 16 + (n & 15);
    const float* fp = feat_T + ((size_t)b * 1024 + pg) * 512 + head * 64;
    float ssf = 0.f, d0 = 0.f, d1 = 0.f, d2 = 0.f, d3 = 0.f;
#pragma unroll
    for (int c4 = 0; c4 < 16; ++c4) {
        F4 fv;
        fv.v = *(const float4*)&fp[c4 * 4];
        const float4 c0 = *(const float4*)&cnl[0][c4 * 4];
        const float4 c1 = *(const float4*)&cnl[1][c4 * 4];
        const float4 c2 = *(const float4*)&cnl[2][c4 * 4];
        const float4 c3 = *(const float4*)&cnl[3][c4 * 4];
        ssf += fv.f[0]*fv.f[0] + fv.f[1]*fv.f[1] + fv.f[2]*fv.f[2] + fv.f[3]*fv.f[3];
        d0 += fv.f[0]*c0.x + fv.f[1]*c0.y + fv.f[2]*c0.z + fv.f[3]*c0.w;
        d1 += fv.f[0]*c1.x + fv.f[1]*c1.y + fv.f[2]*c1.z + fv.f[3]*c1.w;
        d2 += fv.f[0]*c2.x + fv.f[1]*c2.y + fv.f[2]*c2.z + fv.f[3]*c2.w;
        d3 += fv.f[0]*c3.x + fv.f[1]*c3.y + fv.f[2]*c3.z + fv.f[3]*c3.w;
    }
    const float invf = 1.f / fmaxf(sqrtf(ssf), 1e-12f);
    float simv[4];
    simv[0] = d0 * invf;
    simv[1] = d1 * invf;
    simv[2] = d2 * invf;
    simv[3] = d3 * invf;
#pragma unroll
    for (int mm = 0; mm < 4; ++mm)
        simv[mm] = 1.f / (1.f + expf(-(beta + alpha * simv[mm])));
    float best = simv[0], second = -1.f;
    int idx = 0;
#pragma unroll
    for (int mm = 1; mm < 4; ++mm) {
        if (simv[mm] > best) { second = best; best = simv[mm]; idx = mm; }
        else second = fmaxf(second, simv[mm]);
    }
    sidx[n] = idx;
    sbest[n] = best;

    float bsum = best, s2sum = second;
#pragma unroll
    for (int off = 32; off > 0; off >>= 1) {
        bsum += __shfl_xor(bsum, off);
        s2sum += __shfl_xor(s2sum, off);
    }
    if (lane == 0) { red[wv] = bsum; red[4 + wv] = s2sum; }
    __syncthreads();
    if (t == 0) {
        part[bp]        = gsc[0] + gsc[1] + gsc[2] + gsc[3] + gsc[4] + gsc[5] + gsc[6] + gsc[7]
                        + gsc[8] + gsc[9] + gsc[10] + gsc[11] + gsc[12] + gsc[13] + gsc[14] + gsc[15];
        part[1024 + bp] = red[0] + red[1] + red[2] + red[3];
        part[2048 + bp] = red[4] + red[5] + red[6] + red[7];
    }

    {
        const _Float16* vT = value_T + ((size_t)b * 1024) * 512 + head * 64 + cc;
        const int rowbase = (f1 * 16 + wv * 4) * 32 + f2 * 16;
        float ag0 = 0.f, ag1 = 0.f, ag2 = 0.f, ag3 = 0.f;
        int c0i = 0, c1i = 0, c2i = 0, c3i = 0;
#pragma unroll 8
        for (int j = 0; j < 64; ++j) {
            const int nn = wv * 64 + j;
            const int id = sidx[nn];
            const int pgn = rowbase + (j >> 4) * 32 + (j & 15);
            const float v = (float)vT[(size_t)pgn * 512];
            ag0 += (id == 0) ? v : 0.f;  c0i += (id == 0);
            ag1 += (id == 1) ? v : 0.f;  c1i += (id == 1);
            ag2 += (id == 2) ? v : 0.f;  c2i += (id == 2);
            ag3 += (id == 3) ? v : 0.f;  c3i += (id == 3);
        }
        scrt[wv][0][cc] = ag0;
        scrt[wv][1][cc] = ag1;
        scrt[wv][2][cc] = ag2;
        scrt[wv][3][cc] = ag3;
        if (lane == 0) {
            cntw[wv][0] = c0i; cntw[wv][1] = c1i;
            cntw[wv][2] = c2i; cntw[wv][3] = c3i;
        }
    }
    __syncthreads();

    {
        const float a = scrt[0][m][cc] + scrt[1][m][cc] + scrt[2][m][cc] + scrt[3][m][cc];
        const int c = cntw[0][m] + cntw[1][m] + cntw[2][m] + cntw[3][m];
        obuf[m][cc] = (a + vcl[m][cc]) / (float)(c + 1);
    }
    __syncthreads();

    const int cch = (t & 3) * 16;
#pragma unroll
    for (int r = 0; r < 4; ++r) {
        const int nn = r * 64 + (t >> 2);
        const int id = sidx[nn];
        const float bs = sbest[nn];
        const int p = (f1 * 16 + (nn >> 4)) * 32 + f2 * 16 + (nn & 15);
        _Float16* dst = outpT + (((size_t)b * 8 + head) * 1024 + p) * 64 + cch;
        const float4 oa = *(const float4*)&obuf[id][cch];
        const float4 ob = *(const float4*)&obuf[id][cch + 4];
        const float4 oc = *(const float4*)&obuf[id][cch + 8];
        const float4 od = *(const float4*)&obuf[id][cch + 12];
        H8 w0, w1;
        w0.h[0] = (_Float16)(bs * oa.x); w0.h[1] = (_Float16)(bs * oa.y);
        w0.h[2] = (_Float16)(bs * oa.z); w0.h[3] = (_Float16)(bs * oa.w);
        w0.h[4] = (_Float16)(bs * ob.x); w0.h[5] = (_Float16)(bs * ob.y);
        w0.h[6] = (_Float16)(bs * ob.z); w0.h[7] = (_Float16)(bs * ob.w);
        w1.h[0] = (_Float16)(bs * oc.x); w1.h[1] = (_Float16)(bs * oc.y);
        w1.h[2] = (_Float16)(bs * oc.z); w1.h[3] = (_Float16)(bs * oc.w);
        w1.h[4] = (_Float16)(bs * od.x); w1.h[5] = (_Float16)(bs * od.y);
        w1.h[6] = (_Float16)(bs * od.z); w1.h[7] = (_Float16)(bs * od.w);
        *(uint4*)dst = w0.u;
        *(uint4*)(dst + 8) = w1.u;
    }
}

// ---------------- k_proj: r12 exact (128x128 + XCD remap) ----------------
__global__ __launch_bounds__(256) void k_proj(
    const float* __restrict__ w, const float* __restrict__ bias,
    const _Float16* __restrict__ outpT,
    const float* __restrict__ part,
    float* __restrict__ dout)
{
    __shared__ _Float16 As[2][4096], Bs[2][4096];
    __shared__ float fin[12];
    const int t = threadIdx.x, lane = t & 63, wv = t >> 6;

    const int bid = blockIdx.x;
    const int r_ = bid & 31;
    const int yy = r_ >> 3;
    const int v_ = (bid >> 5) * 8 + (r_ & 7);
    const int xx = v_ & 7, zz = v_ >> 3;

    if (bid == 0) {
        float so = part[t] + part[t + 256] + part[t + 512] + part[t + 768];
        float sc = part[1024 + t] + part[1280 + t] + part[1536 + t] + part[1792 + t];
        float sp = part[2048 + t] + part[2304 + t] + part[2560 + t] + part[2816 + t];
#pragma unroll
        for (int off = 32; off > 0; off >>= 1) {
            so += __shfl_xor(so, off);
            sc += __shfl_xor(sc, off);
            sp += __shfl_xor(sp, off);
        }
        if (lane == 0) { fin[wv] = so; fin[4 + wv] = sc; fin[8 + wv] = sp; }
        __syncthreads();
        if (t == 0) {
            dout[16777216]     = (fin[0] + fin[1] + fin[2] + fin[3]) / 16384.f;
            dout[16777216 + 1] = -(fin[4] + fin[5] + fin[6] + fin[7]) / 262144.f;
            dout[16777216 + 2] = (fin[8] + fin[9] + fin[10] + fin[11]) / 262144.f;
        }
        __syncthreads();
    }

    const int b = zz, o0 = yy * 128, p0 = xx * 128;
    const int wr = wv >> 1, wc = wv & 1;

    f32x4 acc[4][4];
#pragma unroll
    for (int i = 0; i < 4; ++i)
#pragma unroll
        for (int j = 0; j < 4; ++j) acc[i][j] = (f32x4){0.f, 0.f, 0.f, 0.f};

    const int gslot = ((lane & 3) ^ ((lane >> 3) & 3)) * 8;
    const int srow = p0 + wv * 32 + (lane >> 2);
    const int arow_l = t >> 3;
    const int aq = t & 7;
    const int aqs = aq ^ (((t >> 4) & 3) << 1);

    F4 av[4];
#define LOADA(k0)                                                        \
    {                                                                    \
        _Pragma("unroll")                                                \
        for (int j = 0; j < 4; ++j)                                      \
            av[j].v = *(const float4*)&w[(size_t)(o0 + j * 32 + arow_l) * 512 + (k0) + aq * 4]; \
    }
#define WRITEA(d)                                                        \
    {                                                                    \
        _Pragma("unroll")                                                \
        for (int j = 0; j < 4; ++j) {                                    \
            H4 hh;                                                       \
            _Pragma("unroll")                                            \
            for (int i = 0; i < 4; ++i) hh.h[i] = (_Float16)(av[j].f[i] * 256.f); \
            *(uint2*)&As[(d)][(j * 32 + arow_l) * 32 + aqs * 4] = hh.u;  \
        }                                                                \
    }
#define STAGEB(d, kb)                                                    \
    {                                                                    \
        const _Float16* bsrc = outpT + (((size_t)b * 8 + ((kb) >> 1)) * 1024 + srow) * 64 \
                               + ((kb) & 1) * 32 + gslot;                \
        gld16(bsrc,        &Bs[(d)][(wv * 32) * 32]);                    \
        gld16(bsrc + 1024, &Bs[(d)][(wv * 32 + 16) * 32]);               \
    }

    LOADA(0);
    STAGEB(0, 0);
    WRITEA(0);
    __syncthreads();
    const int slA = ((lane >> 4) ^ ((lane >> 1) & 3)) * 8;
    int cur = 0;
    for (int kb = 0; kb < 16; ++kb) {
        if (kb < 15) {
            LOADA((kb + 1) * 32);
            STAGEB(cur ^ 1, kb + 1);
        }
        f16x8 ah4[4], bh4[4];
#pragma unroll
        for (int i = 0; i < 4; ++i) {
            ah4[i] = *(f16x8*)&As[cur][(wr * 64 + i * 16 + (lane & 15)) * 32 + slA];
            bh4[i] = *(f16x8*)&Bs[cur][(wc * 64 + i * 16 + (lane & 15)) * 32 + slA];
        }
#pragma unroll
        for (int mi = 0; mi < 4; ++mi)
#pragma unroll
            for (int nj = 0; nj < 4; ++nj)
                acc[mi][nj] = __builtin_amdgcn_mfma_f32_16x16x32_f16(ah4[mi], bh4[nj], acc[mi][nj], 0, 0, 0);
        if (kb < 15) WRITEA(cur ^ 1);
        __syncthreads();
        cur ^= 1;
    }
#undef LOADA
#undef WRITEA
#undef STAGEB

#pragma unroll
    for (int mi = 0; mi < 4; ++mi)
#pragma unroll
        for (int r = 0; r < 4; ++r) {
            const int o = o0 + wr * 64 + mi * 16 + (lane >> 4) * 4 + r;
            const float bs = bias[o];
#pragma unroll
            for (int nj = 0; nj < 4; ++nj) {
                const int p = p0 + wc * 64 + nj * 16 + (lane & 15);
                dout[((size_t)b * 512 + o) * HW + p] = acc[mi][nj][r] * (1.f / 256.f) + bs;
            }
        }
}

extern "C" void kernel_launch(void* const* d_in, const int* in_sizes, int n_in,
                              void* d_out, int out_size, void* d_ws, size_t ws_size,
                              hipStream_t stream)
{
    const float* x   = (const float*)d_in[0];
    const float* f_w = (const float*)d_in[1];
    const float* f_b = (const float*)d_in[2];
    const float* v_w = (const float*)d_in[3];
    const float* v_b = (const float*)d_in[4];
    const float* p_w = (const float*)d_in[5];
    const float* p_b = (const float*)d_in[6];
    const float* s_a = (const float*)d_in[7];
    const float* s_b = (const float*)d_in[8];
    float* out = (float*)d_out;

    char* ws = (char*)d_ws;
    float*     feat_T  = (float*)ws;                                   // [0, 64M)
    _Float16*  xh      = (_Float16*)(ws + (size_t)64 * 1024 * 1024);   // [64M, 96M)
    _Float16*  xl      = (_Float16*)(ws + (size_t)96 * 1024 * 1024);   // [96M, 128M)
    _Float16*  outpT   = xh;                                           // reuse after featval
    _Float16*  value_T = xl;                                           // reuse after featval
    float*     part    = (float*)(ws + (size_t)128 * 1024 * 1024);     // 12 KB

    // scratch in d_out (ALL consumed by k_featval/k_cluster before k_proj writes)
    _Float16* fwh       = (_Float16*)out;                 // 512 KB
    _Float16* fwl       = (_Float16*)(out + 131072);      // 512 KB
    _Float16* vwh       = (_Float16*)(out + 262144);      // 512 KB
    float*    centers_f = out + 524288;                   // 2 MB
    float*    centers_v = out + 1048576;                  // 2 MB

    k_xsplit <<<dim3(16, 8, 32), 256, 0, stream>>>(x, xh, xl, f_w, v_w, fwh, fwl, vwh);
    k_featval<<<dim3(256), 512, 0, stream>>>(fwh, fwl, vwh, f_b, v_b, xh, xl,
                                             feat_T, centers_f, value_T, centers_v);
    k_cluster<<<dim3(1024), 256, 0, stream>>>(feat_T, value_T, centers_f, centers_v,
                                              s_a, s_b, outpT, part);
    k_proj   <<<dim3(1024), 256, 0, stream>>>(p_w, p_b, outpT, part, out);
}

// Round 14
// 179.699 us; speedup vs baseline: 1.0472x; 1.0472x over previous
//
#include <hip/hip_runtime.h>

// ---------------------------------------------------------------------------
// Round 14: revert to r12 (best verified, 180 µs) + vectorized k_xsplit.
//  k_xsplit : float4 x-loads (16B/lane), uint2 fp16 stores (8B), same math.
//  k_featval: r12 exact (counted-vmcnt 2-barrier, T1 XCD remap) — r13's
//             phase-split REVERTED (hurt: 90->101 µs, MfmaUtil 31.6->27.5).
//  k_cluster: r12 exact.  k_proj: r12 exact (128² + T1 remap).
// ws: [0,64M) feat_T | [64M,96M) xh->outpT | [96M,128M) xl->value_T | +12KB part
// d_out scratch (ALL consumed before k_proj writes): fwh fwl vwh centers_f/v
// ---------------------------------------------------------------------------

#define HW 1024

typedef _Float16 f16x8 __attribute__((ext_vector_type(8)));
typedef float f32x4 __attribute__((ext_vector_type(4)));

union H4 { uint2 u; _Float16 h[4]; };
union H8 { uint4 u; _Float16 h[8]; };
union H2 { unsigned int u; _Float16 h[2]; };
union F4 { float4 v; float f[4]; };

__device__ __forceinline__ void gld16(const _Float16* g, _Float16* l) {
    __builtin_amdgcn_global_load_lds(
        (const __attribute__((address_space(1))) void*)g,
        (__attribute__((address_space(3))) void*)l, 16, 0, 0);
}

// ---------------- k_xsplit: transpose + fp16 split (vectorized) + weight pre-split ----------------
__global__ __launch_bounds__(256) void k_xsplit(
    const float* __restrict__ x,
    _Float16* __restrict__ xh, _Float16* __restrict__ xl,
    const float* __restrict__ fw, const float* __restrict__ vw,
    _Float16* __restrict__ fwh, _Float16* __restrict__ fwl,
    _Float16* __restrict__ vwh)
{
    __shared__ float tile[64][65];
    const int t = threadIdx.x;
    const int b = blockIdx.z;
    const int k0 = blockIdx.y * 64;
    const int n0 = blockIdx.x * 64;

    if (b == 0) {   // weight pre-split: 128 blocks x 2 chunks x 256 thr x 4 floats
        const int c0 = (blockIdx.x * 8 + blockIdx.y) * 2;
#pragma unroll
        for (int u = 0; u < 2; ++u) {
            const int i = ((c0 + u) * 256 + t) * 4;
            F4 a;
            a.v = *(const float4*)&fw[i];
            H4 h, l;
#pragma unroll
            for (int j = 0; j < 4; ++j) {
                const float s = a.f[j] * 256.f;
                h.h[j] = (_Float16)s;
                l.h[j] = (_Float16)(s - (float)h.h[j]);
            }
            *(uint2*)&fwh[i] = h.u;
            *(uint2*)&fwl[i] = l.u;
            a.v = *(const float4*)&vw[i];
#pragma unroll
            for (int j = 0; j < 4; ++j) h.h[j] = (_Float16)(a.f[j] * 256.f);
            *(uint2*)&vwh[i] = h.u;
        }
    }

    const float* Xb = x + (size_t)b * (512 * HW);
    // float4 loads: 16B/lane, 4 iterations cover the 64x64 tile
#pragma unroll
    for (int j = 0; j < 4; ++j) {
        const int idx = j * 256 + t;
        const int k = idx >> 4;
        const int n4 = (idx & 15) * 4;
        const float4 v = *(const float4*)&Xb[(size_t)(k0 + k) * HW + n0 + n4];
        tile[k][n4 + 0] = v.x;
        tile[k][n4 + 1] = v.y;
        tile[k][n4 + 2] = v.z;
        tile[k][n4 + 3] = v.w;
    }
    __syncthreads();
    // convert+store: each thread 4 consecutive k -> uint2 (8B) per buffer
#pragma unroll
    for (int j = 0; j < 4; ++j) {
        const int n = j * 16 + (t >> 4);
        const int kq = t & 15;
        H4 hh, hl;
#pragma unroll
        for (int i = 0; i < 4; ++i) {
            const float s = tile[kq * 4 + i][n] * 256.f;
            hh.h[i] = (_Float16)s;
            hl.h[i] = (_Float16)(s - (float)hh.h[i]);
        }
        const size_t o = ((size_t)b * 1024 + n0 + n) * 512 + k0 + kq * 4;
        *(uint2*)&xh[o] = hh.u;
        *(uint2*)&xl[o] = hl.u;
    }
}

// ---------------- k_featval: r12 exact (counted vmcnt + T1 remap) ----------------
__global__ __launch_bounds__(512, 2) void k_featval(
    const _Float16* __restrict__ fwh, const _Float16* __restrict__ fwl,
    const _Float16* __restrict__ vwh,
    const float* __restrict__ f_b, const float* __restrict__ v_b,
    const _Float16* __restrict__ xh, const _Float16* __restrict__ xl,
    float* __restrict__ feat_T, float* __restrict__ centers_f,
    _Float16* __restrict__ value_T, float* __restrict__ centers_v)
{
    __shared__ _Float16 Ah[2][8192], Al[2][8192], Bh[2][8192], Bl[2][8192]; // 128 KB
    __shared__ float pool_lds[4][4][256];                                   // 16 KB
    const int t = threadIdx.x, lane = t & 63, wv = t >> 6;

    // T1 remap: bid = u*16 + r; yy=r>>3; v=u*8+(r&7); xx=v&3; zz=v>>2
    const int bid = blockIdx.x;
    const int r_ = bid & 15, u_ = bid >> 4;
    const int yy = r_ >> 3;
    const int v_ = u_ * 8 + (r_ & 7);
    const int xx = v_ & 3, zz = v_ >> 2;

    const int b = zz, o0 = yy * 256, p0 = xx * 256;
    const int wr = wv >> 2, wc = wv & 3;

    f32x4 acc[8][4];
#pragma unroll
    for (int i = 0; i < 8; ++i)
#pragma unroll
        for (int j = 0; j < 4; ++j) acc[i][j] = (f32x4){0.f, 0.f, 0.f, 0.f};

    const int gslot = ((lane & 3) ^ ((lane >> 3) & 3)) * 8;
    const _Float16* ash = fwh + (size_t)(o0 + wv * 32 + (lane >> 2)) * 512 + gslot;
    const _Float16* asl = fwl + (size_t)(o0 + wv * 32 + (lane >> 2)) * 512 + gslot;
    const _Float16* asv = vwh + (size_t)(o0 + wv * 32 + (lane >> 2)) * 512 + gslot;
    const size_t brow = (size_t)b * 1024 + p0 + wv * 32 + (lane >> 2);
    const _Float16* bsh = xh + brow * 512 + gslot;
    const _Float16* bsl = xl + brow * 512 + gslot;

#define STAGE_F(d, k0)                                              \
    {                                                               \
        gld16(ash + (k0),        &Ah[(d)][(wv * 32) * 32]);         \
        gld16(ash + (k0) + 8192, &Ah[(d)][(wv * 32 + 16) * 32]);    \
        gld16(asl + (k0),        &Al[(d)][(wv * 32) * 32]);         \
        gld16(asl + (k0) + 8192, &Al[(d)][(wv * 32 + 16) * 32]);    \
        gld16(bsh + (k0),        &Bh[(d)][(wv * 32) * 32]);         \
        gld16(bsh + (k0) + 8192, &Bh[(d)][(wv * 32 + 16) * 32]);    \
        gld16(bsl + (k0),        &Bl[(d)][(wv * 32) * 32]);         \
        gld16(bsl + (k0) + 8192, &Bl[(d)][(wv * 32 + 16) * 32]);    \
    }
#define STAGE_W(d, k0)                                              \
    {                                                               \
        gld16(asv + (k0),        &Ah[(d)][(wv * 32) * 32]);         \
        gld16(asv + (k0) + 8192, &Ah[(d)][(wv * 32 + 16) * 32]);    \
        gld16(bsh + (k0),        &Bh[(d)][(wv * 32) * 32]);         \
        gld16(bsh + (k0) + 8192, &Bh[(d)][(wv * 32 + 16) * 32]);    \
    }

    STAGE_F(0, 0);
    const int slA = ((lane >> 4) ^ ((lane >> 1) & 3)) * 8;
    int cur = 0;
    for (int kb = 0; kb < 16; ++kb) {
        if (kb < 15) {
            STAGE_F(cur ^ 1, (kb + 1) * 32);
            asm volatile("s_waitcnt vmcnt(8)" ::: "memory");
        } else {
            asm volatile("s_waitcnt vmcnt(0)" ::: "memory");
        }
        __builtin_amdgcn_sched_barrier(0);
        __builtin_amdgcn_s_barrier();
        f16x8 bh4[4], bl4[4];
#pragma unroll
        for (int j = 0; j < 4; ++j) {
            const int bo = (wc * 64 + j * 16 + (lane & 15)) * 32 + slA;
            bh4[j] = *(f16x8*)&Bh[cur][bo];
            bl4[j] = *(f16x8*)&Bl[cur][bo];
        }
#pragma unroll
        for (int mi = 0; mi < 8; ++mi) {
            const int ao = (wr * 128 + mi * 16 + (lane & 15)) * 32 + slA;
            const f16x8 ah = *(f16x8*)&Ah[cur][ao];
            const f16x8 al = *(f16x8*)&Al[cur][ao];
#pragma unroll
            for (int nj = 0; nj < 4; ++nj) {
                acc[mi][nj] = __builtin_amdgcn_mfma_f32_16x16x32_f16(ah, bh4[nj], acc[mi][nj], 0, 0, 0);
                acc[mi][nj] = __builtin_amdgcn_mfma_f32_16x16x32_f16(ah, bl4[nj], acc[mi][nj], 0, 0, 0);
                acc[mi][nj] = __builtin_amdgcn_mfma_f32_16x16x32_f16(al, bh4[nj], acc[mi][nj], 0, 0, 0);
            }
        }
        __builtin_amdgcn_s_barrier();
        cur ^= 1;
    }

    STAGE_W(0, 0);   // value prologue issued early (T14)

    // ---- feat epilogue ----
    const int pj = (lane >> 3) & 1;
    {
        float ps[32][2];
#pragma unroll
        for (int mi = 0; mi < 8; ++mi) {
            const int obase = o0 + wr * 128 + mi * 16 + (lane >> 4) * 4;
            F4 bs4;
            bs4.v = *(const float4*)&f_b[obase];
#pragma unroll
            for (int r = 0; r < 4; ++r) { ps[mi * 4 + r][0] = 0.f; ps[mi * 4 + r][1] = 0.f; }
#pragma unroll
            for (int nj = 0; nj < 4; ++nj) {
                const int p = p0 + wc * 64 + nj * 16 + (lane & 15);
                F4 vv;
#pragma unroll
                for (int r = 0; r < 4; ++r) {
                    vv.f[r] = acc[mi][nj][r] * (1.f / 65536.f) + bs4.f[r];
                    ps[mi * 4 + r][nj & 1] += vv.f[r];
                }
                *(float4*)&feat_T[((size_t)b * 1024 + p) * 512 + obase] = vv.v;
            }
        }
#pragma unroll
        for (int q = 0; q < 32; ++q)
#pragma unroll
            for (int f2s = 0; f2s < 2; ++f2s) {
                ps[q][f2s] += __shfl_xor(ps[q][f2s], 1);
                ps[q][f2s] += __shfl_xor(ps[q][f2s], 2);
                ps[q][f2s] += __shfl_xor(ps[q][f2s], 4);
            }
        if ((lane & 7) == 0) {
#pragma unroll
            for (int mi = 0; mi < 8; ++mi)
#pragma unroll
                for (int r = 0; r < 4; ++r) {
                    const int ol = wr * 128 + mi * 16 + (lane >> 4) * 4 + r;
                    pool_lds[wc][0 * 2 + pj][ol] = ps[mi * 4 + r][0];
                    pool_lds[wc][1 * 2 + pj][ol] = ps[mi * 4 + r][1];
                }
        }
        __syncthreads();
#pragma unroll
        for (int u = 0; u < 2; ++u) {
            const int idx = u * 512 + t;
            const int g = idx >> 8, o = idx & 255;
            const float s = pool_lds[0][g][o] + pool_lds[1][g][o]
                          + pool_lds[2][g][o] + pool_lds[3][g][o];
            centers_f[(((size_t)b * 8 + 2 * xx) * 4 + g) * 512 + o0 + o] = s;
            centers_f[(((size_t)b * 8 + 2 * xx + 1) * 4 + g) * 512 + o0 + o] = 0.f;
        }
    }

    // ---- fused value K-loop ----
    f32x4 vacc[8][4];
#pragma unroll
    for (int i = 0; i < 8; ++i)
#pragma unroll
        for (int j = 0; j < 4; ++j) vacc[i][j] = (f32x4){0.f, 0.f, 0.f, 0.f};

    cur = 0;
    for (int kb = 0; kb < 16; ++kb) {
        if (kb < 15) {
            STAGE_W(cur ^ 1, (kb + 1) * 32);
            asm volatile("s_waitcnt vmcnt(4)" ::: "memory");
        } else {
            asm volatile("s_waitcnt vmcnt(0)" ::: "memory");
        }
        __builtin_amdgcn_sched_barrier(0);
        __builtin_amdgcn_s_barrier();
        f16x8 bh4[4];
#pragma unroll
        for (int j = 0; j < 4; ++j)
            bh4[j] = *(f16x8*)&Bh[cur][(wc * 64 + j * 16 + (lane & 15)) * 32 + slA];
#pragma unroll
        for (int mi = 0; mi < 8; ++mi) {
            const f16x8 ah = *(f16x8*)&Ah[cur][(wr * 128 + mi * 16 + (lane & 15)) * 32 + slA];
#pragma unroll
            for (int nj = 0; nj < 4; ++nj)
                vacc[mi][nj] = __builtin_amdgcn_mfma_f32_16x16x32_f16(ah, bh4[nj], vacc[mi][nj], 0, 0, 0);
        }
        __builtin_amdgcn_s_barrier();
        cur ^= 1;
    }
#undef STAGE_F
#undef STAGE_W

    // ---- value epilogue ----
    {
        float ps[32][2];
#pragma unroll
        for (int mi = 0; mi < 8; ++mi) {
            const int obase = o0 + wr * 128 + mi * 16 + (lane >> 4) * 4;
            F4 bs4;
            bs4.v = *(const float4*)&v_b[obase];
#pragma unroll
            for (int r = 0; r < 4; ++r) { ps[mi * 4 + r][0] = 0.f; ps[mi * 4 + r][1] = 0.f; }
#pragma unroll
            for (int nj = 0; nj < 4; ++nj) {
                const int p = p0 + wc * 64 + nj * 16 + (lane & 15);
                H4 hv;
#pragma unroll
                for (int r = 0; r < 4; ++r) {
                    const float v = vacc[mi][nj][r] * (1.f / 65536.f) + bs4.f[r];
                    ps[mi * 4 + r][nj & 1] += v;
                    hv.h[r] = (_Float16)v;
                }
                *(uint2*)&value_T[((size_t)b * 1024 + p) * 512 + obase] = hv.u;
            }
        }
#pragma unroll
        for (int q = 0; q < 32; ++q)
#pragma unroll
            for (int f2s = 0; f2s < 2; ++f2s) {
                ps[q][f2s] += __shfl_xor(ps[q][f2s], 1);
                ps[q][f2s] += __shfl_xor(ps[q][f2s], 2);
                ps[q][f2s] += __shfl_xor(ps[q][f2s], 4);
            }
        __syncthreads();
        if ((lane & 7) == 0) {
#pragma unroll
            for (int mi = 0; mi < 8; ++mi)
#pragma unroll
                for (int r = 0; r < 4; ++r) {
                    const int ol = wr * 128 + mi * 16 + (lane >> 4) * 4 + r;
                    pool_lds[wc][0 * 2 + pj][ol] = ps[mi * 4 + r][0];
                    pool_lds[wc][1 * 2 + pj][ol] = ps[mi * 4 + r][1];
                }
        }
        __syncthreads();
#pragma unroll
        for (int u = 0; u < 2; ++u) {
            const int idx = u * 512 + t;
            const int g = idx >> 8, o = idx & 255;
            const float s = pool_lds[0][g][o] + pool_lds[1][g][o]
                          + pool_lds[2][g][o] + pool_lds[3][g][o];
            centers_v[(((size_t)b * 8 + 2 * xx) * 4 + g) * 512 + o0 + o] = s;
            centers_v[(((size_t)b * 8 + 2 * xx + 1) * 4 + g) * 512 + o0 + o] = 0.f;
        }
    }
}

// ---------------- k_cluster: r12 exact ----------------
__global__ __launch_bounds__(256) void k_cluster(
    const float* __restrict__ feat_T, const _Float16* __restrict__ value_T,
    const float* __restrict__ centers_f, const float* __restrict__ centers_v,
    const float* __restrict__ alpha_p, const float* __restrict__ beta_p,
    _Float16* __restrict__ outpT, float* __restrict__ part)
{
    __shared__ float cnl[4][64];
    __shared__ float vcl[4][64];
    __shared__ float obuf[4][68];
    __shared__ int   sidx[256];
    __shared__ float sbest[256];
    __shared__ float scrt[4][4][64];
    __shared__ int   cntw[4][4];
    __shared__ float red[8];
    __shared__ float gsc[16];

    const int t = threadIdx.x, lane = t & 63, wv = t >> 6;
    const int bp = blockIdx.x;
    const int f2 = bp & 1, f1 = (bp >> 1) & 1, head = (bp >> 2) & 7, b = bp >> 5;

    const int m = wv, cc = lane;
    const int pi = m >> 1, pj = m & 1, g = f2 * 2 + pj;
    const int pt = 4 * f1 + 2 * pi;
    {
        const float* cf = centers_f + (((size_t)b * 8 + pt) * 4 + g) * 512 + head * 64 + cc;
        const float c = (cf[0] + cf[4 * 512]) * (1.f / 64.f);
        float ss = c * c;
#pragma unroll
        for (int off = 32; off > 0; off >>= 1) ss += __shfl_xor(ss, off);
        const float inv = 1.f / fmaxf(sqrtf(ss), 1e-12f);
        cnl[m][cc] = c * inv;
        const float* cv = centers_v + (((size_t)b * 8 + pt) * 4 + g) * 512 + head * 64 + cc;
        vcl[m][cc] = (cv[0] + cv[4 * 512]) * (1.f / 64.f);
    }
    __syncthreads();

    if (t < 16) {
        const int gm = t >> 2, gk = t & 3;
        float gg = 0.f;
        for (int c = 0; c < 64; ++c) gg += cnl[gm][c] * cnl[gk][c];
        const float d = gg - (gm == gk ? 1.f : 0.f);
        gsc[t] = d * d;
    }

    const float alpha = alpha_p[0], beta = beta_p[0];
    const int n = t;
    const int pg = (f1 * 16 + (n >> 4)) * 32 + f2 * 16 + (n & 15);
    const float* fp = feat_T + ((size_t)b * 1024 + pg) * 512 + head * 64;
    float ssf = 0.f, d0 = 0.f, d1 = 0.f, d2 = 0.f, d3 = 0.f;
#pragma unroll
    for (int c4 = 0; c4 < 16; ++c4) {
        F4 fv;
        fv.v = *(const float4*)&fp[c4 * 4];
        const float4 c0 = *(const float4*)&cnl[0][c4 * 4];
        const float4 c1 = *(const float4*)&cnl[1][c4 * 4];
        const float4 c2 = *(const float4*)&cnl[2][c4 * 4];
        const float4 c3 = *(const float4*)&cnl[3][c4 * 4];
        ssf += fv.f[0]*fv.f[0] + fv.f[1]*fv.f[1] + fv.f[2]*fv.f[2] + fv.f[3]*fv.f[3];
        d0 += fv.f[0]*c0.x + fv.f[1]*c0.y + fv.f[2]*c0.z + fv.f[3]*c0.w;
        d1 += fv.f[0]*c1.x + fv.f[1]*c1.y + fv.f[2]*c1.z + fv.f[3]*c1.w;
        d2 += fv.f[0]*c2.x + fv.f[1]*c2.y + fv.f[2]*c2.z + fv.f[3]*c2.w;
        d3 += fv.f[0]*c3.x + fv.f[1]*c3.y + fv.f[2]*c3.z + fv.f[3]*c3.w;
    }
    const float invf = 1.f / fmaxf(sqrtf(ssf), 1e-12f);
    float simv[4];
    simv[0] = d0 * invf;
    simv[1] = d1 * invf;
    simv[2] = d2 * invf;
    simv[3] = d3 * invf;
#pragma unroll
    for (int mm = 0; mm < 4; ++mm)
        simv[mm] = 1.f / (1.f + expf(-(beta + alpha * simv[mm])));
    float best = simv[0], second = -1.f;
    int idx = 0;
#pragma unroll
    for (int mm = 1; mm < 4; ++mm) {
        if (simv[mm] > best) { second = best; best = simv[mm]; idx = mm; }
        else second = fmaxf(second, simv[mm]);
    }
    sidx[n] = idx;
    sbest[n] = best;

    float bsum = best, s2sum = second;
#pragma unroll
    for (int off = 32; off > 0; off >>= 1) {
        bsum += __shfl_xor(bsum, off);
        s2sum += __shfl_xor(s2sum, off);
    }
    if (lane == 0) { red[wv] = bsum; red[4 + wv] = s2sum; }
    __syncthreads();
    if (t == 0) {
        part[bp]        = gsc[0] + gsc[1] + gsc[2] + gsc[3] + gsc[4] + gsc[5] + gsc[6] + gsc[7]
                        + gsc[8] + gsc[9] + gsc[10] + gsc[11] + gsc[12] + gsc[13] + gsc[14] + gsc[15];
        part[1024 + bp] = red[0] + red[1] + red[2] + red[3];
        part[2048 + bp] = red[4] + red[5] + red[6] + red[7];
    }

    {
        const _Float16* vT = value_T + ((size_t)b * 1024) * 512 + head * 64 + cc;
        const int rowbase = (f1 * 16 + wv * 4) * 32 + f2 * 16;
        float ag0 = 0.f, ag1 = 0.f, ag2 = 0.f, ag3 = 0.f;
        int c0i = 0, c1i = 0, c2i = 0, c3i = 0;
#pragma unroll 8
        for (int j = 0; j < 64; ++j) {
            const int nn = wv * 64 + j;
            const int id = sidx[nn];
            const int pgn = rowbase + (j >> 4) * 32 + (j & 15);
            const float v = (float)vT[(size_t)pgn * 512];
            ag0 += (id == 0) ? v : 0.f;  c0i += (id == 0);
            ag1 += (id == 1) ? v : 0.f;  c1i += (id == 1);
            ag2 += (id == 2) ? v : 0.f;  c2i += (id == 2);
            ag3 += (id == 3) ? v : 0.f;  c3i += (id == 3);
        }
        scrt[wv][0][cc] = ag0;
        scrt[wv][1][cc] = ag1;
        scrt[wv][2][cc] = ag2;
        scrt[wv][3][cc] = ag3;
        if (lane == 0) {
            cntw[wv][0] = c0i; cntw[wv][1] = c1i;
            cntw[wv][2] = c2i; cntw[wv][3] = c3i;
        }
    }
    __syncthreads();

    {
        const float a = scrt[0][m][cc] + scrt[1][m][cc] + scrt[2][m][cc] + scrt[3][m][cc];
        const int c = cntw[0][m] + cntw[1][m] + cntw[2][m] + cntw[3][m];
        obuf[m][cc] = (a + vcl[m][cc]) / (float)(c + 1);
    }
    __syncthreads();

    const int cch = (t & 3) * 16;
#pragma unroll
    for (int r = 0; r < 4; ++r) {
        const int nn = r * 64 + (t >> 2);
        const int id = sidx[nn];
        const float bs = sbest[nn];
        const int p = (f1 * 16 + (nn >> 4)) * 32 + f2 * 16 + (nn & 15);
        _Float16* dst = outpT + (((size_t)b * 8 + head) * 1024 + p) * 64 + cch;
        const float4 oa = *(const float4*)&obuf[id][cch];
        const float4 ob = *(const float4*)&obuf[id][cch + 4];
        const float4 oc = *(const float4*)&obuf[id][cch + 8];
        const float4 od = *(const float4*)&obuf[id][cch + 12];
        H8 w0, w1;
        w0.h[0] = (_Float16)(bs * oa.x); w0.h[1] = (_Float16)(bs * oa.y);
        w0.h[2] = (_Float16)(bs * oa.z); w0.h[3] = (_Float16)(bs * oa.w);
        w0.h[4] = (_Float16)(bs * ob.x); w0.h[5] = (_Float16)(bs * ob.y);
        w0.h[6] = (_Float16)(bs * ob.z); w0.h[7] = (_Float16)(bs * ob.w);
        w1.h[0] = (_Float16)(bs * oc.x); w1.h[1] = (_Float16)(bs * oc.y);
        w1.h[2] = (_Float16)(bs * oc.z); w1.h[3] = (_Float16)(bs * oc.w);
        w1.h[4] = (_Float16)(bs * od.x); w1.h[5] = (_Float16)(bs * od.y);
        w1.h[6] = (_Float16)(bs * od.z); w1.h[7] = (_Float16)(bs * od.w);
        *(uint4*)dst = w0.u;
        *(uint4*)(dst + 8) = w1.u;
    }
}

// ---------------- k_proj: r12 exact (128x128 + XCD remap) ----------------
__global__ __launch_bounds__(256) void k_proj(
    const float* __restrict__ w, const float* __restrict__ bias,
    const _Float16* __restrict__ outpT,
    const float* __restrict__ part,
    float* __restrict__ dout)
{
    __shared__ _Float16 As[2][4096], Bs[2][4096];
    __shared__ float fin[12];
    const int t = threadIdx.x, lane = t & 63, wv = t >> 6;

    const int bid = blockIdx.x;
    const int r_ = bid & 31;
    const int yy = r_ >> 3;
    const int v_ = (bid >> 5) * 8 + (r_ & 7);
    const int xx = v_ & 7, zz = v_ >> 3;

    if (bid == 0) {
        float so = part[t] + part[t + 256] + part[t + 512] + part[t + 768];
        float sc = part[1024 + t] + part[1280 + t] + part[1536 + t] + part[1792 + t];
        float sp = part[2048 + t] + part[2304 + t] + part[2560 + t] + part[2816 + t];
#pragma unroll
        for (int off = 32; off > 0; off >>= 1) {
            so += __shfl_xor(so, off);
            sc += __shfl_xor(sc, off);
            sp += __shfl_xor(sp, off);
        }
        if (lane == 0) { fin[wv] = so; fin[4 + wv] = sc; fin[8 + wv] = sp; }
        __syncthreads();
        if (t == 0) {
            dout[16777216]     = (fin[0] + fin[1] + fin[2] + fin[3]) / 16384.f;
            dout[16777216 + 1] = -(fin[4] + fin[5] + fin[6] + fin[7]) / 262144.f;
            dout[16777216 + 2] = (fin[8] + fin[9] + fin[10] + fin[11]) / 262144.f;
        }
        __syncthreads();
    }

    const int b = zz, o0 = yy * 128, p0 = xx * 128;
    const int wr = wv >> 1, wc = wv & 1;

    f32x4 acc[4][4];
#pragma unroll
    for (int i = 0; i < 4; ++i)
#pragma unroll
        for (int j = 0; j < 4; ++j) acc[i][j] = (f32x4){0.f, 0.f, 0.f, 0.f};

    const int gslot = ((lane & 3) ^ ((lane >> 3) & 3)) * 8;
    const int srow = p0 + wv * 32 + (lane >> 2);
    const int arow_l = t >> 3;
    const int aq = t & 7;
    const int aqs = aq ^ (((t >> 4) & 3) << 1);

    F4 av[4];
#define LOADA(k0)                                                        \
    {                                                                    \
        _Pragma("unroll")                                                \
        for (int j = 0; j < 4; ++j)                                      \
            av[j].v = *(const float4*)&w[(size_t)(o0 + j * 32 + arow_l) * 512 + (k0) + aq * 4]; \
    }
#define WRITEA(d)                                                        \
    {                                                                    \
        _Pragma("unroll")                                                \
        for (int j = 0; j < 4; ++j) {                                    \
            H4 hh;                                                       \
            _Pragma("unroll")                                            \
            for (int i = 0; i < 4; ++i) hh.h[i] = (_Float16)(av[j].f[i] * 256.f); \
            *(uint2*)&As[(d)][(j * 32 + arow_l) * 32 + aqs * 4] = hh.u;  \
        }                                                                \
    }
#define STAGEB(d, kb)                                                    \
    {                                                                    \
        const _Float16* bsrc = outpT + (((size_t)b * 8 + ((kb) >> 1)) * 1024 + srow) * 64 \
                               + ((kb) & 1) * 32 + gslot;                \
        gld16(bsrc,        &Bs[(d)][(wv * 32) * 32]);                    \
        gld16(bsrc + 1024, &Bs[(d)][(wv * 32 + 16) * 32]);               \
    }

    LOADA(0);
    STAGEB(0, 0);
    WRITEA(0);
    __syncthreads();
    const int slA = ((lane >> 4) ^ ((lane >> 1) & 3)) * 8;
    int cur = 0;
    for (int kb = 0; kb < 16; ++kb) {
        if (kb < 15) {
            LOADA((kb + 1) * 32);
            STAGEB(cur ^ 1, kb + 1);
        }
        f16x8 ah4[4], bh4[4];
#pragma unroll
        for (int i = 0; i < 4; ++i) {
            ah4[i] = *(f16x8*)&As[cur][(wr * 64 + i * 16 + (lane & 15)) * 32 + slA];
            bh4[i] = *(f16x8*)&Bs[cur][(wc * 64 + i * 16 + (lane & 15)) * 32 + slA];
        }
#pragma unroll
        for (int mi = 0; mi < 4; ++mi)
#pragma unroll
            for (int nj = 0; nj < 4; ++nj)
                acc[mi][nj] = __builtin_amdgcn_mfma_f32_16x16x32_f16(ah4[mi], bh4[nj], acc[mi][nj], 0, 0, 0);
        if (kb < 15) WRITEA(cur ^ 1);
        __syncthreads();
        cur ^= 1;
    }
#undef LOADA
#undef WRITEA
#undef STAGEB

#pragma unroll
    for (int mi = 0; mi < 4; ++mi)
#pragma unroll
        for (int r = 0; r < 4; ++r) {
            const int o = o0 + wr * 64 + mi * 16 + (lane >> 4) * 4 + r;
            const float bs = bias[o];
#pragma unroll
            for (int nj = 0; nj < 4; ++nj) {
                const int p = p0 + wc * 64 + nj * 16 + (lane & 15);
                dout[((size_t)b * 512 + o) * HW + p] = acc[mi][nj][r] * (1.f / 256.f) + bs;
            }
        }
}

extern "C" void kernel_launch(void* const* d_in, const int* in_sizes, int n_in,
                              void* d_out, int out_size, void* d_ws, size_t ws_size,
                              hipStream_t stream)
{
    const float* x   = (const float*)d_in[0];
    const float* f_w = (const float*)d_in[1];
    const float* f_b = (const float*)d_in[2];
    const float* v_w = (const float*)d_in[3];
    const float* v_b = (const float*)d_in[4];
    const float* p_w = (const float*)d_in[5];
    const float* p_b = (const float*)d_in[6];
    const float* s_a = (const float*)d_in[7];
    const float* s_b = (const float*)d_in[8];
    float* out = (float*)d_out;

    char* ws = (char*)d_ws;
    float*     feat_T  = (float*)ws;                                   // [0, 64M)
    _Float16*  xh      = (_Float16*)(ws + (size_t)64 * 1024 * 1024);   // [64M, 96M)
    _Float16*  xl      = (_Float16*)(ws + (size_t)96 * 1024 * 1024);   // [96M, 128M)
    _Float16*  outpT   = xh;                                           // reuse after featval
    _Float16*  value_T = xl;                                           // reuse after featval
    float*     part    = (float*)(ws + (size_t)128 * 1024 * 1024);     // 12 KB

    // scratch in d_out (ALL consumed by k_featval/k_cluster before k_proj writes)
    _Float16* fwh       = (_Float16*)out;                 // 512 KB
    _Float16* fwl       = (_Float16*)(out + 131072);      // 512 KB
    _Float16* vwh       = (_Float16*)(out + 262144);      // 512 KB
    float*    centers_f = out + 524288;                   // 2 MB
    float*    centers_v = out + 1048576;                  // 2 MB

    k_xsplit <<<dim3(16, 8, 32), 256, 0, stream>>>(x, xh, xl, f_w, v_w, fwh, fwl, vwh);
    k_featval<<<dim3(256), 512, 0, stream>>>(fwh, fwl, vwh, f_b, v_b, xh, xl,
                                             feat_T, centers_f, value_T, centers_v);
    k_cluster<<<dim3(1024), 256, 0, stream>>>(feat_T, value_T, centers_f, centers_v,
                                              s_a, s_b, outpT, part);
    k_proj   <<<dim3(1024), 256, 0, stream>>>(p_w, p_b, outpT, part, out);
}

// Round 15
// 179.647 us; speedup vs baseline: 1.0475x; 1.0003x over previous
//
#include <hip/hip_runtime.h>

// ---------------------------------------------------------------------------
// Round 14: revert to r12 (best verified, 180 µs) + vectorized k_xsplit.
//  k_xsplit : float4 x-loads (16B/lane), uint2 fp16 stores (8B), same math.
//  k_featval: r12 exact (counted-vmcnt 2-barrier, T1 XCD remap) — r13's
//             phase-split REVERTED (hurt: 90->101 µs, MfmaUtil 31.6->27.5).
//  k_cluster: r12 exact.  k_proj: r12 exact (128² + T1 remap).
// ws: [0,64M) feat_T | [64M,96M) xh->outpT | [96M,128M) xl->value_T | +12KB part
// d_out scratch (ALL consumed before k_proj writes): fwh fwl vwh centers_f/v
// ---------------------------------------------------------------------------

#define HW 1024

typedef _Float16 f16x8 __attribute__((ext_vector_type(8)));
typedef float f32x4 __attribute__((ext_vector_type(4)));

union H4 { uint2 u; _Float16 h[4]; };
union H8 { uint4 u; _Float16 h[8]; };
union H2 { unsigned int u; _Float16 h[2]; };
union F4 { float4 v; float f[4]; };

__device__ __forceinline__ void gld16(const _Float16* g, _Float16* l) {
    __builtin_amdgcn_global_load_lds(
        (const __attribute__((address_space(1))) void*)g,
        (__attribute__((address_space(3))) void*)l, 16, 0, 0);
}

// ---------------- k_xsplit: transpose + fp16 split (vectorized) + weight pre-split ----------------
__global__ __launch_bounds__(256) void k_xsplit(
    const float* __restrict__ x,
    _Float16* __restrict__ xh, _Float16* __restrict__ xl,
    const float* __restrict__ fw, const float* __restrict__ vw,
    _Float16* __restrict__ fwh, _Float16* __restrict__ fwl,
    _Float16* __restrict__ vwh)
{
    __shared__ float tile[64][65];
    const int t = threadIdx.x;
    const int b = blockIdx.z;
    const int k0 = blockIdx.y * 64;
    const int n0 = blockIdx.x * 64;

    if (b == 0) {   // weight pre-split: 128 blocks x 2 chunks x 256 thr x 4 floats
        const int c0 = (blockIdx.x * 8 + blockIdx.y) * 2;
#pragma unroll
        for (int u = 0; u < 2; ++u) {
            const int i = ((c0 + u) * 256 + t) * 4;
            F4 a;
            a.v = *(const float4*)&fw[i];
            H4 h, l;
#pragma unroll
            for (int j = 0; j < 4; ++j) {
                const float s = a.f[j] * 256.f;
                h.h[j] = (_Float16)s;
                l.h[j] = (_Float16)(s - (float)h.h[j]);
            }
            *(uint2*)&fwh[i] = h.u;
            *(uint2*)&fwl[i] = l.u;
            a.v = *(const float4*)&vw[i];
#pragma unroll
            for (int j = 0; j < 4; ++j) h.h[j] = (_Float16)(a.f[j] * 256.f);
            *(uint2*)&vwh[i] = h.u;
        }
    }

    const float* Xb = x + (size_t)b * (512 * HW);
    // float4 loads: 16B/lane, 4 iterations cover the 64x64 tile
#pragma unroll
    for (int j = 0; j < 4; ++j) {
        const int idx = j * 256 + t;
        const int k = idx >> 4;
        const int n4 = (idx & 15) * 4;
        const float4 v = *(const float4*)&Xb[(size_t)(k0 + k) * HW + n0 + n4];
        tile[k][n4 + 0] = v.x;
        tile[k][n4 + 1] = v.y;
        tile[k][n4 + 2] = v.z;
        tile[k][n4 + 3] = v.w;
    }
    __syncthreads();
    // convert+store: each thread 4 consecutive k -> uint2 (8B) per buffer
#pragma unroll
    for (int j = 0; j < 4; ++j) {
        const int n = j * 16 + (t >> 4);
        const int kq = t & 15;
        H4 hh, hl;
#pragma unroll
        for (int i = 0; i < 4; ++i) {
            const float s = tile[kq * 4 + i][n] * 256.f;
            hh.h[i] = (_Float16)s;
            hl.h[i] = (_Float16)(s - (float)hh.h[i]);
        }
        const size_t o = ((size_t)b * 1024 + n0 + n) * 512 + k0 + kq * 4;
        *(uint2*)&xh[o] = hh.u;
        *(uint2*)&xl[o] = hl.u;
    }
}

// ---------------- k_featval: r12 exact (counted vmcnt + T1 remap) ----------------
__global__ __launch_bounds__(512, 2) void k_featval(
    const _Float16* __restrict__ fwh, const _Float16* __restrict__ fwl,
    const _Float16* __restrict__ vwh,
    const float* __restrict__ f_b, const float* __restrict__ v_b,
    const _Float16* __restrict__ xh, const _Float16* __restrict__ xl,
    float* __restrict__ feat_T, float* __restrict__ centers_f,
    _Float16* __restrict__ value_T, float* __restrict__ centers_v)
{
    __shared__ _Float16 Ah[2][8192], Al[2][8192], Bh[2][8192], Bl[2][8192]; // 128 KB
    __shared__ float pool_lds[4][4][256];                                   // 16 KB
    const int t = threadIdx.x, lane = t & 63, wv = t >> 6;

    // T1 remap: bid = u*16 + r; yy=r>>3; v=u*8+(r&7); xx=v&3; zz=v>>2
    const int bid = blockIdx.x;
    const int r_ = bid & 15, u_ = bid >> 4;
    const int yy = r_ >> 3;
    const int v_ = u_ * 8 + (r_ & 7);
    const int xx = v_ & 3, zz = v_ >> 2;

    const int b = zz, o0 = yy * 256, p0 = xx * 256;
    const int wr = wv >> 2, wc = wv & 3;

    f32x4 acc[8][4];
#pragma unroll
    for (int i = 0; i < 8; ++i)
#pragma unroll
        for (int j = 0; j < 4; ++j) acc[i][j] = (f32x4){0.f, 0.f, 0.f, 0.f};

    const int gslot = ((lane & 3) ^ ((lane >> 3) & 3)) * 8;
    const _Float16* ash = fwh + (size_t)(o0 + wv * 32 + (lane >> 2)) * 512 + gslot;
    const _Float16* asl = fwl + (size_t)(o0 + wv * 32 + (lane >> 2)) * 512 + gslot;
    const _Float16* asv = vwh + (size_t)(o0 + wv * 32 + (lane >> 2)) * 512 + gslot;
    const size_t brow = (size_t)b * 1024 + p0 + wv * 32 + (lane >> 2);
    const _Float16* bsh = xh + brow * 512 + gslot;
    const _Float16* bsl = xl + brow * 512 + gslot;

#define STAGE_F(d, k0)                                              \
    {                                                               \
        gld16(ash + (k0),        &Ah[(d)][(wv * 32) * 32]);         \
        gld16(ash + (k0) + 8192, &Ah[(d)][(wv * 32 + 16) * 32]);    \
        gld16(asl + (k0),        &Al[(d)][(wv * 32) * 32]);         \
        gld16(asl + (k0) + 8192, &Al[(d)][(wv * 32 + 16) * 32]);    \
        gld16(bsh + (k0),        &Bh[(d)][(wv * 32) * 32]);         \
        gld16(bsh + (k0) + 8192, &Bh[(d)][(wv * 32 + 16) * 32]);    \
        gld16(bsl + (k0),        &Bl[(d)][(wv * 32) * 32]);         \
        gld16(bsl + (k0) + 8192, &Bl[(d)][(wv * 32 + 16) * 32]);    \
    }
#define STAGE_W(d, k0)                                              \
    {                                                               \
        gld16(asv + (k0),        &Ah[(d)][(wv * 32) * 32]);         \
        gld16(asv + (k0) + 8192, &Ah[(d)][(wv * 32 + 16) * 32]);    \
        gld16(bsh + (k0),        &Bh[(d)][(wv * 32) * 32]);         \
        gld16(bsh + (k0) + 8192, &Bh[(d)][(wv * 32 + 16) * 32]);    \
    }

    STAGE_F(0, 0);
    const int slA = ((lane >> 4) ^ ((lane >> 1) & 3)) * 8;
    int cur = 0;
    for (int kb = 0; kb < 16; ++kb) {
        if (kb < 15) {
            STAGE_F(cur ^ 1, (kb + 1) * 32);
            asm volatile("s_waitcnt vmcnt(8)" ::: "memory");
        } else {
            asm volatile("s_waitcnt vmcnt(0)" ::: "memory");
        }
        __builtin_amdgcn_sched_barrier(0);
        __builtin_amdgcn_s_barrier();
        f16x8 bh4[4], bl4[4];
#pragma unroll
        for (int j = 0; j < 4; ++j) {
            const int bo = (wc * 64 + j * 16 + (lane & 15)) * 32 + slA;
            bh4[j] = *(f16x8*)&Bh[cur][bo];
            bl4[j] = *(f16x8*)&Bl[cur][bo];
        }
#pragma unroll
        for (int mi = 0; mi < 8; ++mi) {
            const int ao = (wr * 128 + mi * 16 + (lane & 15)) * 32 + slA;
            const f16x8 ah = *(f16x8*)&Ah[cur][ao];
            const f16x8 al = *(f16x8*)&Al[cur][ao];
#pragma unroll
            for (int nj = 0; nj < 4; ++nj) {
                acc[mi][nj] = __builtin_amdgcn_mfma_f32_16x16x32_f16(ah, bh4[nj], acc[mi][nj], 0, 0, 0);
                acc[mi][nj] = __builtin_amdgcn_mfma_f32_16x16x32_f16(ah, bl4[nj], acc[mi][nj], 0, 0, 0);
                acc[mi][nj] = __builtin_amdgcn_mfma_f32_16x16x32_f16(al, bh4[nj], acc[mi][nj], 0, 0, 0);
            }
        }
        __builtin_amdgcn_s_barrier();
        cur ^= 1;
    }

    STAGE_W(0, 0);   // value prologue issued early (T14)

    // ---- feat epilogue ----
    const int pj = (lane >> 3) & 1;
    {
        float ps[32][2];
#pragma unroll
        for (int mi = 0; mi < 8; ++mi) {
            const int obase = o0 + wr * 128 + mi * 16 + (lane >> 4) * 4;
            F4 bs4;
            bs4.v = *(const float4*)&f_b[obase];
#pragma unroll
            for (int r = 0; r < 4; ++r) { ps[mi * 4 + r][0] = 0.f; ps[mi * 4 + r][1] = 0.f; }
#pragma unroll
            for (int nj = 0; nj < 4; ++nj) {
                const int p = p0 + wc * 64 + nj * 16 + (lane & 15);
                F4 vv;
#pragma unroll
                for (int r = 0; r < 4; ++r) {
                    vv.f[r] = acc[mi][nj][r] * (1.f / 65536.f) + bs4.f[r];
                    ps[mi * 4 + r][nj & 1] += vv.f[r];
                }
                *(float4*)&feat_T[((size_t)b * 1024 + p) * 512 + obase] = vv.v;
            }
        }
#pragma unroll
        for (int q = 0; q < 32; ++q)
#pragma unroll
            for (int f2s = 0; f2s < 2; ++f2s) {
                ps[q][f2s] += __shfl_xor(ps[q][f2s], 1);
                ps[q][f2s] += __shfl_xor(ps[q][f2s], 2);
                ps[q][f2s] += __shfl_xor(ps[q][f2s], 4);
            }
        if ((lane & 7) == 0) {
#pragma unroll
            for (int mi = 0; mi < 8; ++mi)
#pragma unroll
                for (int r = 0; r < 4; ++r) {
                    const int ol = wr * 128 + mi * 16 + (lane >> 4) * 4 + r;
                    pool_lds[wc][0 * 2 + pj][ol] = ps[mi * 4 + r][0];
                    pool_lds[wc][1 * 2 + pj][ol] = ps[mi * 4 + r][1];
                }
        }
        __syncthreads();
#pragma unroll
        for (int u = 0; u < 2; ++u) {
            const int idx = u * 512 + t;
            const int g = idx >> 8, o = idx & 255;
            const float s = pool_lds[0][g][o] + pool_lds[1][g][o]
                          + pool_lds[2][g][o] + pool_lds[3][g][o];
            centers_f[(((size_t)b * 8 + 2 * xx) * 4 + g) * 512 + o0 + o] = s;
            centers_f[(((size_t)b * 8 + 2 * xx + 1) * 4 + g) * 512 + o0 + o] = 0.f;
        }
    }

    // ---- fused value K-loop ----
    f32x4 vacc[8][4];
#pragma unroll
    for (int i = 0; i < 8; ++i)
#pragma unroll
        for (int j = 0; j < 4; ++j) vacc[i][j] = (f32x4){0.f, 0.f, 0.f, 0.f};

    cur = 0;
    for (int kb = 0; kb < 16; ++kb) {
        if (kb < 15) {
            STAGE_W(cur ^ 1, (kb + 1) * 32);
            asm volatile("s_waitcnt vmcnt(4)" ::: "memory");
        } else {
            asm volatile("s_waitcnt vmcnt(0)" ::: "memory");
        }
        __builtin_amdgcn_sched_barrier(0);
        __builtin_amdgcn_s_barrier();
        f16x8 bh4[4];
#pragma unroll
        for (int j = 0; j < 4; ++j)
            bh4[j] = *(f16x8*)&Bh[cur][(wc * 64 + j * 16 + (lane & 15)) * 32 + slA];
#pragma unroll
        for (int mi = 0; mi < 8; ++mi) {
            const f16x8 ah = *(f16x8*)&Ah[cur][(wr * 128 + mi * 16 + (lane & 15)) * 32 + slA];
#pragma unroll
            for (int nj = 0; nj < 4; ++nj)
                vacc[mi][nj] = __builtin_amdgcn_mfma_f32_16x16x32_f16(ah, bh4[nj], vacc[mi][nj], 0, 0, 0);
        }
        __builtin_amdgcn_s_barrier();
        cur ^= 1;
    }
#undef STAGE_F
#undef STAGE_W

    // ---- value epilogue ----
    {
        float ps[32][2];
#pragma unroll
        for (int mi = 0; mi < 8; ++mi) {
            const int obase = o0 + wr * 128 + mi * 16 + (lane >> 4) * 4;
            F4 bs4;
            bs4.v = *(const float4*)&v_b[obase];
#pragma unroll
            for (int r = 0; r < 4; ++r) { ps[mi * 4 + r][0] = 0.f; ps[mi * 4 + r][1] = 0.f; }
#pragma unroll
            for (int nj = 0; nj < 4; ++nj) {
                const int p = p0 + wc * 64 + nj * 16 + (lane & 15);
                H4 hv;
#pragma unroll
                for (int r = 0; r < 4; ++r) {
                    const float v = vacc[mi][nj][r] * (1.f / 65536.f) + bs4.f[r];
                    ps[mi * 4 + r][nj & 1] += v;
                    hv.h[r] = (_Float16)v;
                }
                *(uint2*)&value_T[((size_t)b * 1024 + p) * 512 + obase] = hv.u;
            }
        }
#pragma unroll
        for (int q = 0; q < 32; ++q)
#pragma unroll
            for (int f2s = 0; f2s < 2; ++f2s) {
                ps[q][f2s] += __shfl_xor(ps[q][f2s], 1);
                ps[q][f2s] += __shfl_xor(ps[q][f2s], 2);
                ps[q][f2s] += __shfl_xor(ps[q][f2s], 4);
            }
        __syncthreads();
        if ((lane & 7) == 0) {
#pragma unroll
            for (int mi = 0; mi < 8; ++mi)
#pragma unroll
                for (int r = 0; r < 4; ++r) {
                    const int ol = wr * 128 + mi * 16 + (lane >> 4) * 4 + r;
                    pool_lds[wc][0 * 2 + pj][ol] = ps[mi * 4 + r][0];
                    pool_lds[wc][1 * 2 + pj][ol] = ps[mi * 4 + r][1];
                }
        }
        __syncthreads();
#pragma unroll
        for (int u = 0; u < 2; ++u) {
            const int idx = u * 512 + t;
            const int g = idx >> 8, o = idx & 255;
            const float s = pool_lds[0][g][o] + pool_lds[1][g][o]
                          + pool_lds[2][g][o] + pool_lds[3][g][o];
            centers_v[(((size_t)b * 8 + 2 * xx) * 4 + g) * 512 + o0 + o] = s;
            centers_v[(((size_t)b * 8 + 2 * xx + 1) * 4 + g) * 512 + o0 + o] = 0.f;
        }
    }
}

// ---------------- k_cluster: r12 exact ----------------
__global__ __launch_bounds__(256) void k_cluster(
    const float* __restrict__ feat_T, const _Float16* __restrict__ value_T,
    const float* __restrict__ centers_f, const float* __restrict__ centers_v,
    const float* __restrict__ alpha_p, const float* __restrict__ beta_p,
    _Float16* __restrict__ outpT, float* __restrict__ part)
{
    __shared__ float cnl[4][64];
    __shared__ float vcl[4][64];
    __shared__ float obuf[4][68];
    __shared__ int   sidx[256];
    __shared__ float sbest[256];
    __shared__ float scrt[4][4][64];
    __shared__ int   cntw[4][4];
    __shared__ float red[8];
    __shared__ float gsc[16];

    const int t = threadIdx.x, lane = t & 63, wv = t >> 6;
    const int bp = blockIdx.x;
    const int f2 = bp & 1, f1 = (bp >> 1) & 1, head = (bp >> 2) & 7, b = bp >> 5;

    const int m = wv, cc = lane;
    const int pi = m >> 1, pj = m & 1, g = f2 * 2 + pj;
    const int pt = 4 * f1 + 2 * pi;
    {
        const float* cf = centers_f + (((size_t)b * 8 + pt) * 4 + g) * 512 + head * 64 + cc;
        const float c = (cf[0] + cf[4 * 512]) * (1.f / 64.f);
        float ss = c * c;
#pragma unroll
        for (int off = 32; off > 0; off >>= 1) ss += __shfl_xor(ss, off);
        const float inv = 1.f / fmaxf(sqrtf(ss), 1e-12f);
        cnl[m][cc] = c * inv;
        const float* cv = centers_v + (((size_t)b * 8 + pt) * 4 + g) * 512 + head * 64 + cc;
        vcl[m][cc] = (cv[0] + cv[4 * 512]) * (1.f / 64.f);
    }
    __syncthreads();

    if (t < 16) {
        const int gm = t >> 2, gk = t & 3;
        float gg = 0.f;
        for (int c = 0; c < 64; ++c) gg += cnl[gm][c] * cnl[gk][c];
        const float d = gg - (gm == gk ? 1.f : 0.f);
        gsc[t] = d * d;
    }

    const float alpha = alpha_p[0], beta = beta_p[0];
    const int n = t;
    const int pg = (f1 * 16 + (n >> 4)) * 32 + f2 * 16 + (n & 15);
    const float* fp = feat_T + ((size_t)b * 1024 + pg) * 512 + head * 64;
    float ssf = 0.f, d0 = 0.f, d1 = 0.f, d2 = 0.f, d3 = 0.f;
#pragma unroll
    for (int c4 = 0; c4 < 16; ++c4) {
        F4 fv;
        fv.v = *(const float4*)&fp[c4 * 4];
        const float4 c0 = *(const float4*)&cnl[0][c4 * 4];
        const float4 c1 = *(const float4*)&cnl[1][c4 * 4];
        const float4 c2 = *(const float4*)&cnl[2][c4 * 4];
        const float4 c3 = *(const float4*)&cnl[3][c4 * 4];
        ssf += fv.f[0]*fv.f[0] + fv.f[1]*fv.f[1] + fv.f[2]*fv.f[2] + fv.f[3]*fv.f[3];
        d0 += fv.f[0]*c0.x + fv.f[1]*c0.y + fv.f[2]*c0.z + fv.f[3]*c0.w;
        d1 += fv.f[0]*c1.x + fv.f[1]*c1.y + fv.f[2]*c1.z + fv.f[3]*c1.w;
        d2 += fv.f[0]*c2.x + fv.f[1]*c2.y + fv.f[2]*c2.z + fv.f[3]*c2.w;
        d3 += fv.f[0]*c3.x + fv.f[1]*c3.y + fv.f[2]*c3.z + fv.f[3]*c3.w;
    }
    const float invf = 1.f / fmaxf(sqrtf(ssf), 1e-12f);
    float simv[4];
    simv[0] = d0 * invf;
    simv[1] = d1 * invf;
    simv[2] = d2 * invf;
    simv[3] = d3 * invf;
#pragma unroll
    for (int mm = 0; mm < 4; ++mm)
        simv[mm] = 1.f / (1.f + expf(-(beta + alpha * simv[mm])));
    float best = simv[0], second = -1.f;
    int idx = 0;
#pragma unroll
    for (int mm = 1; mm < 4; ++mm) {
        if (simv[mm] > best) { second = best; best = simv[mm]; idx = mm; }
        else second = fmaxf(second, simv[mm]);
    }
    sidx[n] = idx;
    sbest[n] = best;

    float bsum = best, s2sum = second;
#pragma unroll
    for (int off = 32; off > 0; off >>= 1) {
        bsum += __shfl_xor(bsum, off);
        s2sum += __shfl_xor(s2sum, off);
    }
    if (lane == 0) { red[wv] = bsum; red[4 + wv] = s2sum; }
    __syncthreads();
    if (t == 0) {
        part[bp]        = gsc[0] + gsc[1] + gsc[2] + gsc[3] + gsc[4] + gsc[5] + gsc[6] + gsc[7]
                        + gsc[8] + gsc[9] + gsc[10] + gsc[11] + gsc[12] + gsc[13] + gsc[14] + gsc[15];
        part[1024 + bp] = red[0] + red[1] + red[2] + red[3];
        part[2048 + bp] = red[4] + red[5] + red[6] + red[7];
    }

    {
        const _Float16* vT = value_T + ((size_t)b * 1024) * 512 + head * 64 + cc;
        const int rowbase = (f1 * 16 + wv * 4) * 32 + f2 * 16;
        float ag0 = 0.f, ag1 = 0.f, ag2 = 0.f, ag3 = 0.f;
        int c0i = 0, c1i = 0, c2i = 0, c3i = 0;
#pragma unroll 8
        for (int j = 0; j < 64; ++j) {
            const int nn = wv * 64 + j;
            const int id = sidx[nn];
            const int pgn = rowbase + (j >> 4) * 32 + (j & 15);
            const float v = (float)vT[(size_t)pgn * 512];
            ag0 += (id == 0) ? v : 0.f;  c0i += (id == 0);
            ag1 += (id == 1) ? v : 0.f;  c1i += (id == 1);
            ag2 += (id == 2) ? v : 0.f;  c2i += (id == 2);
            ag3 += (id == 3) ? v : 0.f;  c3i += (id == 3);
        }
        scrt[wv][0][cc] = ag0;
        scrt[wv][1][cc] = ag1;
        scrt[wv][2][cc] = ag2;
        scrt[wv][3][cc] = ag3;
        if (lane == 0) {
            cntw[wv][0] = c0i; cntw[wv][1] = c1i;
            cntw[wv][2] = c2i; cntw[wv][3] = c3i;
        }
    }
    __syncthreads();

    {
        const float a = scrt[0][m][cc] + scrt[1][m][cc] + scrt[2][m][cc] + scrt[3][m][cc];
        const int c = cntw[0][m] + cntw[1][m] + cntw[2][m] + cntw[3][m];
        obuf[m][cc] = (a + vcl[m][cc]) / (float)(c + 1);
    }
    __syncthreads();

    const int cch = (t & 3) * 16;
#pragma unroll
    for (int r = 0; r < 4; ++r) {
        const int nn = r * 64 + (t >> 2);
        const int id = sidx[nn];
        const float bs = sbest[nn];
        const int p = (f1 * 16 + (nn >> 4)) * 32 + f2 * 16 + (nn & 15);
        _Float16* dst = outpT + (((size_t)b * 8 + head) * 1024 + p) * 64 + cch;
        const float4 oa = *(const float4*)&obuf[id][cch];
        const float4 ob = *(const float4*)&obuf[id][cch + 4];
        const float4 oc = *(const float4*)&obuf[id][cch + 8];
        const float4 od = *(const float4*)&obuf[id][cch + 12];
        H8 w0, w1;
        w0.h[0] = (_Float16)(bs * oa.x); w0.h[1] = (_Float16)(bs * oa.y);
        w0.h[2] = (_Float16)(bs * oa.z); w0.h[3] = (_Float16)(bs * oa.w);
        w0.h[4] = (_Float16)(bs * ob.x); w0.h[5] = (_Float16)(bs * ob.y);
        w0.h[6] = (_Float16)(bs * ob.z); w0.h[7] = (_Float16)(bs * ob.w);
        w1.h[0] = (_Float16)(bs * oc.x); w1.h[1] = (_Float16)(bs * oc.y);
        w1.h[2] = (_Float16)(bs * oc.z); w1.h[3] = (_Float16)(bs * oc.w);
        w1.h[4] = (_Float16)(bs * od.x); w1.h[5] = (_Float16)(bs * od.y);
        w1.h[6] = (_Float16)(bs * od.z); w1.h[7] = (_Float16)(bs * od.w);
        *(uint4*)dst = w0.u;
        *(uint4*)(dst + 8) = w1.u;
    }
}

// ---------------- k_proj: r12 exact (128x128 + XCD remap) ----------------
__global__ __launch_bounds__(256) void k_proj(
    const float* __restrict__ w, const float* __restrict__ bias,
    const _Float16* __restrict__ outpT,
    const float* __restrict__ part,
    float* __restrict__ dout)
{
    __shared__ _Float16 As[2][4096], Bs[2][4096];
    __shared__ float fin[12];
    const int t = threadIdx.x, lane = t & 63, wv = t >> 6;

    const int bid = blockIdx.x;
    const int r_ = bid & 31;
    const int yy = r_ >> 3;
    const int v_ = (bid >> 5) * 8 + (r_ & 7);
    const int xx = v_ & 7, zz = v_ >> 3;

    if (bid == 0) {
        float so = part[t] + part[t + 256] + part[t + 512] + part[t + 768];
        float sc = part[1024 + t] + part[1280 + t] + part[1536 + t] + part[1792 + t];
        float sp = part[2048 + t] + part[2304 + t] + part[2560 + t] + part[2816 + t];
#pragma unroll
        for (int off = 32; off > 0; off >>= 1) {
            so += __shfl_xor(so, off);
            sc += __shfl_xor(sc, off);
            sp += __shfl_xor(sp, off);
        }
        if (lane == 0) { fin[wv] = so; fin[4 + wv] = sc; fin[8 + wv] = sp; }
        __syncthreads();
        if (t == 0) {
            dout[16777216]     = (fin[0] + fin[1] + fin[2] + fin[3]) / 16384.f;
            dout[16777216 + 1] = -(fin[4] + fin[5] + fin[6] + fin[7]) / 262144.f;
            dout[16777216 + 2] = (fin[8] + fin[9] + fin[10] + fin[11]) / 262144.f;
        }
        __syncthreads();
    }

    const int b = zz, o0 = yy * 128, p0 = xx * 128;
    const int wr = wv >> 1, wc = wv & 1;

    f32x4 acc[4][4];
#pragma unroll
    for (int i = 0; i < 4; ++i)
#pragma unroll
        for (int j = 0; j < 4; ++j) acc[i][j] = (f32x4){0.f, 0.f, 0.f, 0.f};

    const int gslot = ((lane & 3) ^ ((lane >> 3) & 3)) * 8;
    const int srow = p0 + wv * 32 + (lane >> 2);
    const int arow_l = t >> 3;
    const int aq = t & 7;
    const int aqs = aq ^ (((t >> 4) & 3) << 1);

    F4 av[4];
#define LOADA(k0)                                                        \
    {                                                                    \
        _Pragma("unroll")                                                \
        for (int j = 0; j < 4; ++j)                                      \
            av[j].v = *(const float4*)&w[(size_t)(o0 + j * 32 + arow_l) * 512 + (k0) + aq * 4]; \
    }
#define WRITEA(d)                                                        \
    {                                                                    \
        _Pragma("unroll")                                                \
        for (int j = 0; j < 4; ++j) {                                    \
            H4 hh;                                                       \
            _Pragma("unroll")                                            \
            for (int i = 0; i < 4; ++i) hh.h[i] = (_Float16)(av[j].f[i] * 256.f); \
            *(uint2*)&As[(d)][(j * 32 + arow_l) * 32 + aqs * 4] = hh.u;  \
        }                                                                \
    }
#define STAGEB(d, kb)                                                    \
    {                                                                    \
        const _Float16* bsrc = outpT + (((size_t)b * 8 + ((kb) >> 1)) * 1024 + srow) * 64 \
                               + ((kb) & 1) * 32 + gslot;                \
        gld16(bsrc,        &Bs[(d)][(wv * 32) * 32]);                    \
        gld16(bsrc + 1024, &Bs[(d)][(wv * 32 + 16) * 32]);               \
    }

    LOADA(0);
    STAGEB(0, 0);
    WRITEA(0);
    __syncthreads();
    const int slA = ((lane >> 4) ^ ((lane >> 1) & 3)) * 8;
    int cur = 0;
    for (int kb = 0; kb < 16; ++kb) {
        if (kb < 15) {
            LOADA((kb + 1) * 32);
            STAGEB(cur ^ 1, kb + 1);
        }
        f16x8 ah4[4], bh4[4];
#pragma unroll
        for (int i = 0; i < 4; ++i) {
            ah4[i] = *(f16x8*)&As[cur][(wr * 64 + i * 16 + (lane & 15)) * 32 + slA];
            bh4[i] = *(f16x8*)&Bs[cur][(wc * 64 + i * 16 + (lane & 15)) * 32 + slA];
        }
#pragma unroll
        for (int mi = 0; mi < 4; ++mi)
#pragma unroll
            for (int nj = 0; nj < 4; ++nj)
                acc[mi][nj] = __builtin_amdgcn_mfma_f32_16x16x32_f16(ah4[mi], bh4[nj], acc[mi][nj], 0, 0, 0);
        if (kb < 15) WRITEA(cur ^ 1);
        __syncthreads();
        cur ^= 1;
    }
#undef LOADA
#undef WRITEA
#undef STAGEB

#pragma unroll
    for (int mi = 0; mi < 4; ++mi)
#pragma unroll
        for (int r = 0; r < 4; ++r) {
            const int o = o0 + wr * 64 + mi * 16 + (lane >> 4) * 4 + r;
            const float bs = bias[o];
#pragma unroll
            for (int nj = 0; nj < 4; ++nj) {
                const int p = p0 + wc * 64 + nj * 16 + (lane & 15);
                dout[((size_t)b * 512 + o) * HW + p] = acc[mi][nj][r] * (1.f / 256.f) + bs;
            }
        }
}

extern "C" void kernel_launch(void* const* d_in, const int* in_sizes, int n_in,
                              void* d_out, int out_size, void* d_ws, size_t ws_size,
                              hipStream_t stream)
{
    const float* x   = (const float*)d_in[0];
    const float* f_w = (const float*)d_in[1];
    const float* f_b = (const float*)d_in[2];
    const float* v_w = (const float*)d_in[3];
    const float* v_b = (const float*)d_in[4];
    const float* p_w = (const float*)d_in[5];
    const float* p_b = (const float*)d_in[6];
    const float* s_a = (const float*)d_in[7];
    const float* s_b = (const float*)d_in[8];
    float* out = (float*)d_out;

    char* ws = (char*)d_ws;
    float*     feat_T  = (float*)ws;                                   // [0, 64M)
    _Float16*  xh      = (_Float16*)(ws + (size_t)64 * 1024 * 1024);   // [64M, 96M)
    _Float16*  xl      = (_Float16*)(ws + (size_t)96 * 1024 * 1024);   // [96M, 128M)
    _Float16*  outpT   = xh;                                           // reuse after featval
    _Float16*  value_T = xl;                                           // reuse after featval
    float*     part    = (float*)(ws + (size_t)128 * 1024 * 1024);     // 12 KB

    // scratch in d_out (ALL consumed by k_featval/k_cluster before k_proj writes)
    _Float16* fwh       = (_Float16*)out;                 // 512 KB
    _Float16* fwl       = (_Float16*)(out + 131072);      // 512 KB
    _Float16* vwh       = (_Float16*)(out + 262144);      // 512 KB
    float*    centers_f = out + 524288;                   // 2 MB
    float*    centers_v = out + 1048576;                  // 2 MB

    k_xsplit <<<dim3(16, 8, 32), 256, 0, stream>>>(x, xh, xl, f_w, v_w, fwh, fwl, vwh);
    k_featval<<<dim3(256), 512, 0, stream>>>(fwh, fwl, vwh, f_b, v_b, xh, xl,
                                             feat_T, centers_f, value_T, centers_v);
    k_cluster<<<dim3(1024), 256, 0, stream>>>(feat_T, value_T, centers_f, centers_v,
                                              s_a, s_b, outpT, part);
    k_proj   <<<dim3(1024), 256, 0, stream>>>(p_w, p_b, outpT, part, out);
}

// Round 16
// 171.497 us; speedup vs baseline: 1.0973x; 1.0475x over previous
//
#include <hip/hip_runtime.h>

// ---------------------------------------------------------------------------
// Round 16: r15 base + k_proj A-staging via pre-split pwh (r9 design, LEGAL
// placement this time: pwh overwrites the DEAD value_T region after k_cluster).
//  k_xsplit : r15 (vectorized transpose/split + folded weight pre-split)
//  k_featval: r12/r15 exact
//  k_cluster: r12/r15 exact
//  k_psplit : NEW tiny kernel (after k_cluster): p_w -> pwh fp16 x256
//  k_proj   : gld16 A-staging from pwh + counted vmcnt(4) (r9 loop + T1 remap)
// ws: [0,64M) feat_T | [64M,96M) xh->outpT | [96M,128M) xl->value_T->pwh | +12KB
// d_out scratch (consumed before k_proj writes): fwh fwl vwh centers_f/v
// ---------------------------------------------------------------------------

#define HW 1024

typedef _Float16 f16x8 __attribute__((ext_vector_type(8)));
typedef float f32x4 __attribute__((ext_vector_type(4)));

union H4 { uint2 u; _Float16 h[4]; };
union H8 { uint4 u; _Float16 h[8]; };
union H2 { unsigned int u; _Float16 h[2]; };
union F4 { float4 v; float f[4]; };

__device__ __forceinline__ void gld16(const _Float16* g, _Float16* l) {
    __builtin_amdgcn_global_load_lds(
        (const __attribute__((address_space(1))) void*)g,
        (__attribute__((address_space(3))) void*)l, 16, 0, 0);
}

// ---------------- k_xsplit: transpose + fp16 split (vectorized) + weight pre-split ----------------
__global__ __launch_bounds__(256) void k_xsplit(
    const float* __restrict__ x,
    _Float16* __restrict__ xh, _Float16* __restrict__ xl,
    const float* __restrict__ fw, const float* __restrict__ vw,
    _Float16* __restrict__ fwh, _Float16* __restrict__ fwl,
    _Float16* __restrict__ vwh)
{
    __shared__ float tile[64][65];
    const int t = threadIdx.x;
    const int b = blockIdx.z;
    const int k0 = blockIdx.y * 64;
    const int n0 = blockIdx.x * 64;

    if (b == 0) {
        const int c0 = (blockIdx.x * 8 + blockIdx.y) * 2;
#pragma unroll
        for (int u = 0; u < 2; ++u) {
            const int i = ((c0 + u) * 256 + t) * 4;
            F4 a;
            a.v = *(const float4*)&fw[i];
            H4 h, l;
#pragma unroll
            for (int j = 0; j < 4; ++j) {
                const float s = a.f[j] * 256.f;
                h.h[j] = (_Float16)s;
                l.h[j] = (_Float16)(s - (float)h.h[j]);
            }
            *(uint2*)&fwh[i] = h.u;
            *(uint2*)&fwl[i] = l.u;
            a.v = *(const float4*)&vw[i];
#pragma unroll
            for (int j = 0; j < 4; ++j) h.h[j] = (_Float16)(a.f[j] * 256.f);
            *(uint2*)&vwh[i] = h.u;
        }
    }

    const float* Xb = x + (size_t)b * (512 * HW);
#pragma unroll
    for (int j = 0; j < 4; ++j) {
        const int idx = j * 256 + t;
        const int k = idx >> 4;
        const int n4 = (idx & 15) * 4;
        const float4 v = *(const float4*)&Xb[(size_t)(k0 + k) * HW + n0 + n4];
        tile[k][n4 + 0] = v.x;
        tile[k][n4 + 1] = v.y;
        tile[k][n4 + 2] = v.z;
        tile[k][n4 + 3] = v.w;
    }
    __syncthreads();
#pragma unroll
    for (int j = 0; j < 4; ++j) {
        const int n = j * 16 + (t >> 4);
        const int kq = t & 15;
        H4 hh, hl;
#pragma unroll
        for (int i = 0; i < 4; ++i) {
            const float s = tile[kq * 4 + i][n] * 256.f;
            hh.h[i] = (_Float16)s;
            hl.h[i] = (_Float16)(s - (float)hh.h[i]);
        }
        const size_t o = ((size_t)b * 1024 + n0 + n) * 512 + k0 + kq * 4;
        *(uint2*)&xh[o] = hh.u;
        *(uint2*)&xl[o] = hl.u;
    }
}

// ---------------- k_featval: r12/r15 exact (counted vmcnt + T1 remap) ----------------
__global__ __launch_bounds__(512, 2) void k_featval(
    const _Float16* __restrict__ fwh, const _Float16* __restrict__ fwl,
    const _Float16* __restrict__ vwh,
    const float* __restrict__ f_b, const float* __restrict__ v_b,
    const _Float16* __restrict__ xh, const _Float16* __restrict__ xl,
    float* __restrict__ feat_T, float* __restrict__ centers_f,
    _Float16* __restrict__ value_T, float* __restrict__ centers_v)
{
    __shared__ _Float16 Ah[2][8192], Al[2][8192], Bh[2][8192], Bl[2][8192]; // 128 KB
    __shared__ float pool_lds[4][4][256];                                   // 16 KB
    const int t = threadIdx.x, lane = t & 63, wv = t >> 6;

    const int bid = blockIdx.x;
    const int r_ = bid & 15, u_ = bid >> 4;
    const int yy = r_ >> 3;
    const int v_ = u_ * 8 + (r_ & 7);
    const int xx = v_ & 3, zz = v_ >> 2;

    const int b = zz, o0 = yy * 256, p0 = xx * 256;
    const int wr = wv >> 2, wc = wv & 3;

    f32x4 acc[8][4];
#pragma unroll
    for (int i = 0; i < 8; ++i)
#pragma unroll
        for (int j = 0; j < 4; ++j) acc[i][j] = (f32x4){0.f, 0.f, 0.f, 0.f};

    const int gslot = ((lane & 3) ^ ((lane >> 3) & 3)) * 8;
    const _Float16* ash = fwh + (size_t)(o0 + wv * 32 + (lane >> 2)) * 512 + gslot;
    const _Float16* asl = fwl + (size_t)(o0 + wv * 32 + (lane >> 2)) * 512 + gslot;
    const _Float16* asv = vwh + (size_t)(o0 + wv * 32 + (lane >> 2)) * 512 + gslot;
    const size_t brow = (size_t)b * 1024 + p0 + wv * 32 + (lane >> 2);
    const _Float16* bsh = xh + brow * 512 + gslot;
    const _Float16* bsl = xl + brow * 512 + gslot;

#define STAGE_F(d, k0)                                              \
    {                                                               \
        gld16(ash + (k0),        &Ah[(d)][(wv * 32) * 32]);         \
        gld16(ash + (k0) + 8192, &Ah[(d)][(wv * 32 + 16) * 32]);    \
        gld16(asl + (k0),        &Al[(d)][(wv * 32) * 32]);         \
        gld16(asl + (k0) + 8192, &Al[(d)][(wv * 32 + 16) * 32]);    \
        gld16(bsh + (k0),        &Bh[(d)][(wv * 32) * 32]);         \
        gld16(bsh + (k0) + 8192, &Bh[(d)][(wv * 32 + 16) * 32]);    \
        gld16(bsl + (k0),        &Bl[(d)][(wv * 32) * 32]);         \
        gld16(bsl + (k0) + 8192, &Bl[(d)][(wv * 32 + 16) * 32]);    \
    }
#define STAGE_W(d, k0)                                              \
    {                                                               \
        gld16(asv + (k0),        &Ah[(d)][(wv * 32) * 32]);         \
        gld16(asv + (k0) + 8192, &Ah[(d)][(wv * 32 + 16) * 32]);    \
        gld16(bsh + (k0),        &Bh[(d)][(wv * 32) * 32]);         \
        gld16(bsh + (k0) + 8192, &Bh[(d)][(wv * 32 + 16) * 32]);    \
    }

    STAGE_F(0, 0);
    const int slA = ((lane >> 4) ^ ((lane >> 1) & 3)) * 8;
    int cur = 0;
    for (int kb = 0; kb < 16; ++kb) {
        if (kb < 15) {
            STAGE_F(cur ^ 1, (kb + 1) * 32);
            asm volatile("s_waitcnt vmcnt(8)" ::: "memory");
        } else {
            asm volatile("s_waitcnt vmcnt(0)" ::: "memory");
        }
        __builtin_amdgcn_sched_barrier(0);
        __builtin_amdgcn_s_barrier();
        f16x8 bh4[4], bl4[4];
#pragma unroll
        for (int j = 0; j < 4; ++j) {
            const int bo = (wc * 64 + j * 16 + (lane & 15)) * 32 + slA;
            bh4[j] = *(f16x8*)&Bh[cur][bo];
            bl4[j] = *(f16x8*)&Bl[cur][bo];
        }
#pragma unroll
        for (int mi = 0; mi < 8; ++mi) {
            const int ao = (wr * 128 + mi * 16 + (lane & 15)) * 32 + slA;
            const f16x8 ah = *(f16x8*)&Ah[cur][ao];
            const f16x8 al = *(f16x8*)&Al[cur][ao];
#pragma unroll
            for (int nj = 0; nj < 4; ++nj) {
                acc[mi][nj] = __builtin_amdgcn_mfma_f32_16x16x32_f16(ah, bh4[nj], acc[mi][nj], 0, 0, 0);
                acc[mi][nj] = __builtin_amdgcn_mfma_f32_16x16x32_f16(ah, bl4[nj], acc[mi][nj], 0, 0, 0);
                acc[mi][nj] = __builtin_amdgcn_mfma_f32_16x16x32_f16(al, bh4[nj], acc[mi][nj], 0, 0, 0);
            }
        }
        __builtin_amdgcn_s_barrier();
        cur ^= 1;
    }

    STAGE_W(0, 0);   // value prologue issued early (T14)

    // ---- feat epilogue ----
    const int pj = (lane >> 3) & 1;
    {
        float ps[32][2];
#pragma unroll
        for (int mi = 0; mi < 8; ++mi) {
            const int obase = o0 + wr * 128 + mi * 16 + (lane >> 4) * 4;
            F4 bs4;
            bs4.v = *(const float4*)&f_b[obase];
#pragma unroll
            for (int r = 0; r < 4; ++r) { ps[mi * 4 + r][0] = 0.f; ps[mi * 4 + r][1] = 0.f; }
#pragma unroll
            for (int nj = 0; nj < 4; ++nj) {
                const int p = p0 + wc * 64 + nj * 16 + (lane & 15);
                F4 vv;
#pragma unroll
                for (int r = 0; r < 4; ++r) {
                    vv.f[r] = acc[mi][nj][r] * (1.f / 65536.f) + bs4.f[r];
                    ps[mi * 4 + r][nj & 1] += vv.f[r];
                }
                *(float4*)&feat_T[((size_t)b * 1024 + p) * 512 + obase] = vv.v;
            }
        }
#pragma unroll
        for (int q = 0; q < 32; ++q)
#pragma unroll
            for (int f2s = 0; f2s < 2; ++f2s) {
                ps[q][f2s] += __shfl_xor(ps[q][f2s], 1);
                ps[q][f2s] += __shfl_xor(ps[q][f2s], 2);
                ps[q][f2s] += __shfl_xor(ps[q][f2s], 4);
            }
        if ((lane & 7) == 0) {
#pragma unroll
            for (int mi = 0; mi < 8; ++mi)
#pragma unroll
                for (int r = 0; r < 4; ++r) {
                    const int ol = wr * 128 + mi * 16 + (lane >> 4) * 4 + r;
                    pool_lds[wc][0 * 2 + pj][ol] = ps[mi * 4 + r][0];
                    pool_lds[wc][1 * 2 + pj][ol] = ps[mi * 4 + r][1];
                }
        }
        __syncthreads();
#pragma unroll
        for (int u = 0; u < 2; ++u) {
            const int idx = u * 512 + t;
            const int g = idx >> 8, o = idx & 255;
            const float s = pool_lds[0][g][o] + pool_lds[1][g][o]
                          + pool_lds[2][g][o] + pool_lds[3][g][o];
            centers_f[(((size_t)b * 8 + 2 * xx) * 4 + g) * 512 + o0 + o] = s;
            centers_f[(((size_t)b * 8 + 2 * xx + 1) * 4 + g) * 512 + o0 + o] = 0.f;
        }
    }

    // ---- fused value K-loop ----
    f32x4 vacc[8][4];
#pragma unroll
    for (int i = 0; i < 8; ++i)
#pragma unroll
        for (int j = 0; j < 4; ++j) vacc[i][j] = (f32x4){0.f, 0.f, 0.f, 0.f};

    cur = 0;
    for (int kb = 0; kb < 16; ++kb) {
        if (kb < 15) {
            STAGE_W(cur ^ 1, (kb + 1) * 32);
            asm volatile("s_waitcnt vmcnt(4)" ::: "memory");
        } else {
            asm volatile("s_waitcnt vmcnt(0)" ::: "memory");
        }
        __builtin_amdgcn_sched_barrier(0);
        __builtin_amdgcn_s_barrier();
        f16x8 bh4[4];
#pragma unroll
        for (int j = 0; j < 4; ++j)
            bh4[j] = *(f16x8*)&Bh[cur][(wc * 64 + j * 16 + (lane & 15)) * 32 + slA];
#pragma unroll
        for (int mi = 0; mi < 8; ++mi) {
            const f16x8 ah = *(f16x8*)&Ah[cur][(wr * 128 + mi * 16 + (lane & 15)) * 32 + slA];
#pragma unroll
            for (int nj = 0; nj < 4; ++nj)
                vacc[mi][nj] = __builtin_amdgcn_mfma_f32_16x16x32_f16(ah, bh4[nj], vacc[mi][nj], 0, 0, 0);
        }
        __builtin_amdgcn_s_barrier();
        cur ^= 1;
    }
#undef STAGE_F
#undef STAGE_W

    // ---- value epilogue ----
    {
        float ps[32][2];
#pragma unroll
        for (int mi = 0; mi < 8; ++mi) {
            const int obase = o0 + wr * 128 + mi * 16 + (lane >> 4) * 4;
            F4 bs4;
            bs4.v = *(const float4*)&v_b[obase];
#pragma unroll
            for (int r = 0; r < 4; ++r) { ps[mi * 4 + r][0] = 0.f; ps[mi * 4 + r][1] = 0.f; }
#pragma unroll
            for (int nj = 0; nj < 4; ++nj) {
                const int p = p0 + wc * 64 + nj * 16 + (lane & 15);
                H4 hv;
#pragma unroll
                for (int r = 0; r < 4; ++r) {
                    const float v = vacc[mi][nj][r] * (1.f / 65536.f) + bs4.f[r];
                    ps[mi * 4 + r][nj & 1] += v;
                    hv.h[r] = (_Float16)v;
                }
                *(uint2*)&value_T[((size_t)b * 1024 + p) * 512 + obase] = hv.u;
            }
        }
#pragma unroll
        for (int q = 0; q < 32; ++q)
#pragma unroll
            for (int f2s = 0; f2s < 2; ++f2s) {
                ps[q][f2s] += __shfl_xor(ps[q][f2s], 1);
                ps[q][f2s] += __shfl_xor(ps[q][f2s], 2);
                ps[q][f2s] += __shfl_xor(ps[q][f2s], 4);
            }
        __syncthreads();
        if ((lane & 7) == 0) {
#pragma unroll
            for (int mi = 0; mi < 8; ++mi)
#pragma unroll
                for (int r = 0; r < 4; ++r) {
                    const int ol = wr * 128 + mi * 16 + (lane >> 4) * 4 + r;
                    pool_lds[wc][0 * 2 + pj][ol] = ps[mi * 4 + r][0];
                    pool_lds[wc][1 * 2 + pj][ol] = ps[mi * 4 + r][1];
                }
        }
        __syncthreads();
#pragma unroll
        for (int u = 0; u < 2; ++u) {
            const int idx = u * 512 + t;
            const int g = idx >> 8, o = idx & 255;
            const float s = pool_lds[0][g][o] + pool_lds[1][g][o]
                          + pool_lds[2][g][o] + pool_lds[3][g][o];
            centers_v[(((size_t)b * 8 + 2 * xx) * 4 + g) * 512 + o0 + o] = s;
            centers_v[(((size_t)b * 8 + 2 * xx + 1) * 4 + g) * 512 + o0 + o] = 0.f;
        }
    }
}

// ---------------- k_cluster: r12/r15 exact ----------------
__global__ __launch_bounds__(256) void k_cluster(
    const float* __restrict__ feat_T, const _Float16* __restrict__ value_T,
    const float* __restrict__ centers_f, const float* __restrict__ centers_v,
    const float* __restrict__ alpha_p, const float* __restrict__ beta_p,
    _Float16* __restrict__ outpT, float* __restrict__ part)
{
    __shared__ float cnl[4][64];
    __shared__ float vcl[4][64];
    __shared__ float obuf[4][68];
    __shared__ int   sidx[256];
    __shared__ float sbest[256];
    __shared__ float scrt[4][4][64];
    __shared__ int   cntw[4][4];
    __shared__ float red[8];
    __shared__ float gsc[16];

    const int t = threadIdx.x, lane = t & 63, wv = t >> 6;
    const int bp = blockIdx.x;
    const int f2 = bp & 1, f1 = (bp >> 1) & 1, head = (bp >> 2) & 7, b = bp >> 5;

    const int m = wv, cc = lane;
    const int pi = m >> 1, pj = m & 1, g = f2 * 2 + pj;
    const int pt = 4 * f1 + 2 * pi;
    {
        const float* cf = centers_f + (((size_t)b * 8 + pt) * 4 + g) * 512 + head * 64 + cc;
        const float c = (cf[0] + cf[4 * 512]) * (1.f / 64.f);
        float ss = c * c;
#pragma unroll
        for (int off = 32; off > 0; off >>= 1) ss += __shfl_xor(ss, off);
        const float inv = 1.f / fmaxf(sqrtf(ss), 1e-12f);
        cnl[m][cc] = c * inv;
        const float* cv = centers_v + (((size_t)b * 8 + pt) * 4 + g) * 512 + head * 64 + cc;
        vcl[m][cc] = (cv[0] + cv[4 * 512]) * (1.f / 64.f);
    }
    __syncthreads();

    if (t < 16) {
        const int gm = t >> 2, gk = t & 3;
        float gg = 0.f;
        for (int c = 0; c < 64; ++c) gg += cnl[gm][c] * cnl[gk][c];
        const float d = gg - (gm == gk ? 1.f : 0.f);
        gsc[t] = d * d;
    }

    const float alpha = alpha_p[0], beta = beta_p[0];
    const int n = t;
    const int pg = (f1 * 16 + (n >> 4)) * 32 + f2 * 16 + (n & 15);
    const float* fp = feat_T + ((size_t)b * 1024 + pg) * 512 + head * 64;
    float ssf = 0.f, d0 = 0.f, d1 = 0.f, d2 = 0.f, d3 = 0.f;
#pragma unroll
    for (int c4 = 0; c4 < 16; ++c4) {
        F4 fv;
        fv.v = *(const float4*)&fp[c4 * 4];
        const float4 c0 = *(const float4*)&cnl[0][c4 * 4];
        const float4 c1 = *(const float4*)&cnl[1][c4 * 4];
        const float4 c2 = *(const float4*)&cnl[2][c4 * 4];
        const float4 c3 = *(const float4*)&cnl[3][c4 * 4];
        ssf += fv.f[0]*fv.f[0] + fv.f[1]*fv.f[1] + fv.f[2]*fv.f[2] + fv.f[3]*fv.f[3];
        d0 += fv.f[0]*c0.x + fv.f[1]*c0.y + fv.f[2]*c0.z + fv.f[3]*c0.w;
        d1 += fv.f[0]*c1.x + fv.f[1]*c1.y + fv.f[2]*c1.z + fv.f[3]*c1.w;
        d2 += fv.f[0]*c2.x + fv.f[1]*c2.y + fv.f[2]*c2.z + fv.f[3]*c2.w;
        d3 += fv.f[0]*c3.x + fv.f[1]*c3.y + fv.f[2]*c3.z + fv.f[3]*c3.w;
    }
    const float invf = 1.f / fmaxf(sqrtf(ssf), 1e-12f);
    float simv[4];
    simv[0] = d0 * invf;
    simv[1] = d1 * invf;
    simv[2] = d2 * invf;
    simv[3] = d3 * invf;
#pragma unroll
    for (int mm = 0; mm < 4; ++mm)
        simv[mm] = 1.f / (1.f + expf(-(beta + alpha * simv[mm])));
    float best = simv[0], second = -1.f;
    int idx = 0;
#pragma unroll
    for (int mm = 1; mm < 4; ++mm) {
        if (simv[mm] > best) { second = best; best = simv[mm]; idx = mm; }
        else second = fmaxf(second, simv[mm]);
    }
    sidx[n] = idx;
    sbest[n] = best;

    float bsum = best, s2sum = second;
#pragma unroll
    for (int off = 32; off > 0; off >>= 1) {
        bsum += __shfl_xor(bsum, off);
        s2sum += __shfl_xor(s2sum, off);
    }
    if (lane == 0) { red[wv] = bsum; red[4 + wv] = s2sum; }
    __syncthreads();
    if (t == 0) {
        part[bp]        = gsc[0] + gsc[1] + gsc[2] + gsc[3] + gsc[4] + gsc[5] + gsc[6] + gsc[7]
                        + gsc[8] + gsc[9] + gsc[10] + gsc[11] + gsc[12] + gsc[13] + gsc[14] + gsc[15];
        part[1024 + bp] = red[0] + red[1] + red[2] + red[3];
        part[2048 + bp] = red[4] + red[5] + red[6] + red[7];
    }

    {
        const _Float16* vT = value_T + ((size_t)b * 1024) * 512 + head * 64 + cc;
        const int rowbase = (f1 * 16 + wv * 4) * 32 + f2 * 16;
        float ag0 = 0.f, ag1 = 0.f, ag2 = 0.f, ag3 = 0.f;
        int c0i = 0, c1i = 0, c2i = 0, c3i = 0;
#pragma unroll 8
        for (int j = 0; j < 64; ++j) {
            const int nn = wv * 64 + j;
            const int id = sidx[nn];
            const int pgn = rowbase + (j >> 4) * 32 + (j & 15);
            const float v = (float)vT[(size_t)pgn * 512];
            ag0 += (id == 0) ? v : 0.f;  c0i += (id == 0);
            ag1 += (id == 1) ? v : 0.f;  c1i += (id == 1);
            ag2 += (id == 2) ? v : 0.f;  c2i += (id == 2);
            ag3 += (id == 3) ? v : 0.f;  c3i += (id == 3);
        }
        scrt[wv][0][cc] = ag0;
        scrt[wv][1][cc] = ag1;
        scrt[wv][2][cc] = ag2;
        scrt[wv][3][cc] = ag3;
        if (lane == 0) {
            cntw[wv][0] = c0i; cntw[wv][1] = c1i;
            cntw[wv][2] = c2i; cntw[wv][3] = c3i;
        }
    }
    __syncthreads();

    {
        const float a = scrt[0][m][cc] + scrt[1][m][cc] + scrt[2][m][cc] + scrt[3][m][cc];
        const int c = cntw[0][m] + cntw[1][m] + cntw[2][m] + cntw[3][m];
        obuf[m][cc] = (a + vcl[m][cc]) / (float)(c + 1);
    }
    __syncthreads();

    const int cch = (t & 3) * 16;
#pragma unroll
    for (int r = 0; r < 4; ++r) {
        const int nn = r * 64 + (t >> 2);
        const int id = sidx[nn];
        const float bs = sbest[nn];
        const int p = (f1 * 16 + (nn >> 4)) * 32 + f2 * 16 + (nn & 15);
        _Float16* dst = outpT + (((size_t)b * 8 + head) * 1024 + p) * 64 + cch;
        const float4 oa = *(const float4*)&obuf[id][cch];
        const float4 ob = *(const float4*)&obuf[id][cch + 4];
        const float4 oc = *(const float4*)&obuf[id][cch + 8];
        const float4 od = *(const float4*)&obuf[id][cch + 12];
        H8 w0, w1;
        w0.h[0] = (_Float16)(bs * oa.x); w0.h[1] = (_Float16)(bs * oa.y);
        w0.h[2] = (_Float16)(bs * oa.z); w0.h[3] = (_Float16)(bs * oa.w);
        w0.h[4] = (_Float16)(bs * ob.x); w0.h[5] = (_Float16)(bs * ob.y);
        w0.h[6] = (_Float16)(bs * ob.z); w0.h[7] = (_Float16)(bs * ob.w);
        w1.h[0] = (_Float16)(bs * oc.x); w1.h[1] = (_Float16)(bs * oc.y);
        w1.h[2] = (_Float16)(bs * oc.z); w1.h[3] = (_Float16)(bs * oc.w);
        w1.h[4] = (_Float16)(bs * od.x); w1.h[5] = (_Float16)(bs * od.y);
        w1.h[6] = (_Float16)(bs * od.z); w1.h[7] = (_Float16)(bs * od.w);
        *(uint4*)dst = w0.u;
        *(uint4*)(dst + 8) = w1.u;
    }
}

// ---------------- k_psplit: p_w -> pwh fp16 (after k_cluster; pwh over dead value_T) ----------------
__global__ __launch_bounds__(256) void k_psplit(
    const float* __restrict__ pw, _Float16* __restrict__ pwh)
{
    const int i = (blockIdx.x * 256 + threadIdx.x) * 4;
    F4 a;
    a.v = *(const float4*)&pw[i];
    H4 h;
#pragma unroll
    for (int j = 0; j < 4; ++j) h.h[j] = (_Float16)(a.f[j] * 256.f);
    *(uint2*)&pwh[i] = h.u;
}

// ---------------- k_proj: gld16 A-staging (pwh) + counted vmcnt + T1 remap ----------------
__global__ __launch_bounds__(256) void k_proj(
    const _Float16* __restrict__ pwh, const float* __restrict__ bias,
    const _Float16* __restrict__ outpT,
    const float* __restrict__ part,
    float* __restrict__ dout)
{
    __shared__ _Float16 As[2][4096], Bs[2][4096];
    __shared__ float fin[12];
    const int t = threadIdx.x, lane = t & 63, wv = t >> 6;

    // T1 remap: r=bid&31; yy=r>>3; v=(bid>>5)*8+(r&7); xx=v&7; zz=v>>3
    const int bid = blockIdx.x;
    const int r_ = bid & 31;
    const int yy = r_ >> 3;
    const int v_ = (bid >> 5) * 8 + (r_ & 7);
    const int xx = v_ & 7, zz = v_ >> 3;

    if (bid == 0) {
        float so = part[t] + part[t + 256] + part[t + 512] + part[t + 768];
        float sc = part[1024 + t] + part[1280 + t] + part[1536 + t] + part[1792 + t];
        float sp = part[2048 + t] + part[2304 + t] + part[2560 + t] + part[2816 + t];
#pragma unroll
        for (int off = 32; off > 0; off >>= 1) {
            so += __shfl_xor(so, off);
            sc += __shfl_xor(sc, off);
            sp += __shfl_xor(sp, off);
        }
        if (lane == 0) { fin[wv] = so; fin[4 + wv] = sc; fin[8 + wv] = sp; }
        __syncthreads();
        if (t == 0) {
            dout[16777216]     = (fin[0] + fin[1] + fin[2] + fin[3]) / 16384.f;
            dout[16777216 + 1] = -(fin[4] + fin[5] + fin[6] + fin[7]) / 262144.f;
            dout[16777216 + 2] = (fin[8] + fin[9] + fin[10] + fin[11]) / 262144.f;
        }
        __syncthreads();
    }

    const int b = zz, o0 = yy * 128, p0 = xx * 128;
    const int wr = wv >> 1, wc = wv & 1;

    f32x4 acc[4][4];
#pragma unroll
    for (int i = 0; i < 4; ++i)
#pragma unroll
        for (int j = 0; j < 4; ++j) acc[i][j] = (f32x4){0.f, 0.f, 0.f, 0.f};

    const int gslot = ((lane & 3) ^ ((lane >> 3) & 3)) * 8;
    const _Float16* ash = pwh + (size_t)(o0 + wv * 32 + (lane >> 2)) * 512 + gslot;
    const int srow = p0 + wv * 32 + (lane >> 2);

#define STAGE_P(d, kb)                                                   \
    {                                                                    \
        gld16(ash + (kb) * 32,        &As[(d)][(wv * 32) * 32]);         \
        gld16(ash + (kb) * 32 + 8192, &As[(d)][(wv * 32 + 16) * 32]);    \
        const _Float16* bsrc = outpT + (((size_t)b * 8 + ((kb) >> 1)) * 1024 + srow) * 64 \
                               + ((kb) & 1) * 32 + gslot;                \
        gld16(bsrc,        &Bs[(d)][(wv * 32) * 32]);                    \
        gld16(bsrc + 1024, &Bs[(d)][(wv * 32 + 16) * 32]);               \
    }

    STAGE_P(0, 0);
    const int slA = ((lane >> 4) ^ ((lane >> 1) & 3)) * 8;
    int cur = 0;
    for (int kb = 0; kb < 16; ++kb) {
        if (kb < 15) {
            STAGE_P(cur ^ 1, kb + 1);
            asm volatile("s_waitcnt vmcnt(4)" ::: "memory");
        } else {
            asm volatile("s_waitcnt vmcnt(0)" ::: "memory");
        }
        __builtin_amdgcn_sched_barrier(0);
        __builtin_amdgcn_s_barrier();
        f16x8 ah4[4], bh4[4];
#pragma unroll
        for (int i = 0; i < 4; ++i) {
            ah4[i] = *(f16x8*)&As[cur][(wr * 64 + i * 16 + (lane & 15)) * 32 + slA];
            bh4[i] = *(f16x8*)&Bs[cur][(wc * 64 + i * 16 + (lane & 15)) * 32 + slA];
        }
#pragma unroll
        for (int mi = 0; mi < 4; ++mi)
#pragma unroll
            for (int nj = 0; nj < 4; ++nj)
                acc[mi][nj] = __builtin_amdgcn_mfma_f32_16x16x32_f16(ah4[mi], bh4[nj], acc[mi][nj], 0, 0, 0);
        __builtin_amdgcn_s_barrier();
        cur ^= 1;
    }
#undef STAGE_P

#pragma unroll
    for (int mi = 0; mi < 4; ++mi)
#pragma unroll
        for (int r = 0; r < 4; ++r) {
            const int o = o0 + wr * 64 + mi * 16 + (lane >> 4) * 4 + r;
            const float bs = bias[o];
#pragma unroll
            for (int nj = 0; nj < 4; ++nj) {
                const int p = p0 + wc * 64 + nj * 16 + (lane & 15);
                dout[((size_t)b * 512 + o) * HW + p] = acc[mi][nj][r] * (1.f / 256.f) + bs;
            }
        }
}

extern "C" void kernel_launch(void* const* d_in, const int* in_sizes, int n_in,
                              void* d_out, int out_size, void* d_ws, size_t ws_size,
                              hipStream_t stream)
{
    const float* x   = (const float*)d_in[0];
    const float* f_w = (const float*)d_in[1];
    const float* f_b = (const float*)d_in[2];
    const float* v_w = (const float*)d_in[3];
    const float* v_b = (const float*)d_in[4];
    const float* p_w = (const float*)d_in[5];
    const float* p_b = (const float*)d_in[6];
    const float* s_a = (const float*)d_in[7];
    const float* s_b = (const float*)d_in[8];
    float* out = (float*)d_out;

    char* ws = (char*)d_ws;
    float*     feat_T  = (float*)ws;                                   // [0, 64M)
    _Float16*  xh      = (_Float16*)(ws + (size_t)64 * 1024 * 1024);   // [64M, 96M)
    _Float16*  xl      = (_Float16*)(ws + (size_t)96 * 1024 * 1024);   // [96M, 128M)
    _Float16*  outpT   = xh;                                           // reuse after featval
    _Float16*  value_T = xl;                                           // reuse after featval
    _Float16*  pwh     = xl;                                           // reuse after k_cluster (value_T dead)
    float*     part    = (float*)(ws + (size_t)128 * 1024 * 1024);     // 12 KB

    // scratch in d_out (ALL consumed by k_featval/k_cluster before k_proj writes)
    _Float16* fwh       = (_Float16*)out;                 // 512 KB
    _Float16* fwl       = (_Float16*)(out + 131072);      // 512 KB
    _Float16* vwh       = (_Float16*)(out + 262144);      // 512 KB
    float*    centers_f = out + 524288;                   // 2 MB
    float*    centers_v = out + 1048576;                  // 2 MB

    k_xsplit <<<dim3(16, 8, 32), 256, 0, stream>>>(x, xh, xl, f_w, v_w, fwh, fwl, vwh);
    k_featval<<<dim3(256), 512, 0, stream>>>(fwh, fwl, vwh, f_b, v_b, xh, xl,
                                             feat_T, centers_f, value_T, centers_v);
    k_cluster<<<dim3(1024), 256, 0, stream>>>(feat_T, value_T, centers_f, centers_v,
                                              s_a, s_b, outpT, part);
    k_psplit <<<dim3(256), 256, 0, stream>>>(p_w, pwh);
    k_proj   <<<dim3(1024), 256, 0, stream>>>(pwh, p_b, outpT, part, out);
}